// Round 3
// baseline (4750.217 us; speedup 1.0000x reference)
//
#include <hip/hip_runtime.h>
#include <math.h>

#define B_ 2
#define S_ 2048
#define E_ 1024
#define H_ 8
#define DH_ 64
#define DA_ 512
#define DMLP_ 2048
#define SCALE_ 0.04419417382415922f   // 1/sqrt(512)
#define LN_EPS_ 1e-5f

// ---------------------------------------------------------------------------
// Per-row LN stats: stats[2*row] = mean, stats[2*row+1] = rsqrt(var+eps).
// One block per row (E=1024), 256 threads, float4 each. Single pass E[x^2].
// ---------------------------------------------------------------------------
__global__ __launch_bounds__(256)
void ln_stats(const float* __restrict__ x, float* __restrict__ stats)
{
    __shared__ float sm[10];
    const int row = blockIdx.x;
    const int tid = threadIdx.x;
    const float4 v = reinterpret_cast<const float4*>(x + (size_t)row * E_)[tid];
    float s = v.x + v.y + v.z + v.w;
    float q = v.x * v.x + v.y * v.y + v.z * v.z + v.w * v.w;
    #pragma unroll
    for (int o = 32; o > 0; o >>= 1) {
        s += __shfl_down(s, o);
        q += __shfl_down(q, o);
    }
    const int wid = tid >> 6, lane = tid & 63;
    if (lane == 0) { sm[wid] = s; sm[4 + wid] = q; }
    __syncthreads();
    if (tid == 0) {
        const float ts = sm[0] + sm[1] + sm[2] + sm[3];
        const float tq = sm[4] + sm[5] + sm[6] + sm[7];
        const float mu = ts * (1.0f / E_);
        const float var = tq * (1.0f / E_) - mu * mu;
        stats[2 * row]     = mu;
        stats[2 * row + 1] = rsqrtf(var + LN_EPS_);
    }
}

// ---------------------------------------------------------------------------
// fp32 tiled GEMM: out = epilogue(op(A) @ W). A: MxK row-major, W: KxN row-major.
// If LNA: op(A)[r][c] = (A[r][c]-mu[r])*rstd[r]*lng[c]+lnb[c] applied at stage.
// 128x128 tile, BK=8, 256 threads, 8x8 per thread.
// MODE 0: +bias, exact gelu, row-major out              (fc1)
// MODE 1: +bias, +res, row-major out                    (fc2)
// MODE 2: scatter to (b,h,s,d) with RoPE                (q/k proj)
// MODE 3: scatter to (b,h,s,d), no RoPE                 (v proj)
// MODE 4: +res, row-major out                           (attn out proj)
// ---------------------------------------------------------------------------
#define GBM 128
#define GBN 128
#define GBK 8

template<int MODE, bool LNA>
__global__ __launch_bounds__(256)
void gemm_f32(const float* __restrict__ A, const float* __restrict__ W,
              const float* __restrict__ bias, const float* res,
              float* out,
              const float* __restrict__ stats, const float* __restrict__ lng,
              const float* __restrict__ lnb, int M, int N, int K)
{
    __shared__ float sA[GBK][GBM + 4];
    __shared__ float sB[GBK][GBN + 4];
    const int tid = threadIdx.x;
    const int tx = tid & 15;
    const int ty = tid >> 4;
    const int bm = blockIdx.y * GBM;
    const int bn = blockIdx.x * GBN;

    float acc[8][8];
    #pragma unroll
    for (int i = 0; i < 8; ++i)
        #pragma unroll
        for (int j = 0; j < 8; ++j) acc[i][j] = 0.f;

    const int am = tid >> 1;          // 0..127 : A tile row
    const int ak = (tid & 1) * 4;     // 0 or 4 : A tile col (k)
    const int bk = tid >> 5;          // 0..7   : B tile row (k)
    const int bn4 = (tid & 31) * 4;   // B tile col

    float amu = 0.f, ars = 0.f;
    if constexpr (LNA) {
        const int arow = bm + am;
        amu = stats[2 * arow];
        ars = stats[2 * arow + 1];
    }

    for (int k0 = 0; k0 < K; k0 += GBK) {
        float4 a4 = *reinterpret_cast<const float4*>(A + (size_t)(bm + am) * K + k0 + ak);
        if constexpr (LNA) {
            const float4 g4 = *reinterpret_cast<const float4*>(lng + k0 + ak);
            const float4 h4 = *reinterpret_cast<const float4*>(lnb + k0 + ak);
            a4.x = (a4.x - amu) * ars * g4.x + h4.x;
            a4.y = (a4.y - amu) * ars * g4.y + h4.y;
            a4.z = (a4.z - amu) * ars * g4.z + h4.z;
            a4.w = (a4.w - amu) * ars * g4.w + h4.w;
        }
        const float4 b4 = *reinterpret_cast<const float4*>(W + (size_t)(k0 + bk) * N + bn + bn4);
        sA[ak + 0][am] = a4.x;
        sA[ak + 1][am] = a4.y;
        sA[ak + 2][am] = a4.z;
        sA[ak + 3][am] = a4.w;
        *reinterpret_cast<float4*>(&sB[bk][bn4]) = b4;
        __syncthreads();
        #pragma unroll
        for (int kk = 0; kk < GBK; ++kk) {
            const float4 a0 = *reinterpret_cast<const float4*>(&sA[kk][ty * 8]);
            const float4 a1 = *reinterpret_cast<const float4*>(&sA[kk][ty * 8 + 4]);
            const float4 b0 = *reinterpret_cast<const float4*>(&sB[kk][tx * 8]);
            const float4 b1 = *reinterpret_cast<const float4*>(&sB[kk][tx * 8 + 4]);
            const float av[8] = {a0.x, a0.y, a0.z, a0.w, a1.x, a1.y, a1.z, a1.w};
            const float bv[8] = {b0.x, b0.y, b0.z, b0.w, b1.x, b1.y, b1.z, b1.w};
            #pragma unroll
            for (int i = 0; i < 8; ++i)
                #pragma unroll
                for (int j = 0; j < 8; ++j)
                    acc[i][j] = fmaf(av[i], bv[j], acc[i][j]);
        }
        __syncthreads();
    }

    const int r0 = bm + ty * 8;
    const int c0 = bn + tx * 8;

    if constexpr (MODE == 0 || MODE == 1) {
        float bias0[8];
        #pragma unroll
        for (int j = 0; j < 8; ++j) bias0[j] = bias[c0 + j];
        #pragma unroll
        for (int i = 0; i < 8; ++i) {
            const size_t off = (size_t)(r0 + i) * N + c0;
            float v[8];
            #pragma unroll
            for (int j = 0; j < 8; ++j) v[j] = acc[i][j] + bias0[j];
            if constexpr (MODE == 0) {
                #pragma unroll
                for (int j = 0; j < 8; ++j)
                    v[j] = 0.5f * v[j] * (1.0f + erff(v[j] * 0.70710678118654752f));
            } else {
                const float4 ra = *reinterpret_cast<const float4*>(res + off);
                const float4 rb = *reinterpret_cast<const float4*>(res + off + 4);
                v[0] += ra.x; v[1] += ra.y; v[2] += ra.z; v[3] += ra.w;
                v[4] += rb.x; v[5] += rb.y; v[6] += rb.z; v[7] += rb.w;
            }
            *reinterpret_cast<float4*>(out + off) = make_float4(v[0], v[1], v[2], v[3]);
            *reinterpret_cast<float4*>(out + off + 4) = make_float4(v[4], v[5], v[6], v[7]);
        }
    } else if constexpr (MODE == 2 || MODE == 3) {
        const int hh = c0 >> 6;
        const int d0 = c0 & 63;
        #pragma unroll
        for (int i = 0; i < 8; ++i) {
            const int r = r0 + i;
            const int bidx = r >> 11;
            const int pos = r & (S_ - 1);
            float v[8];
            #pragma unroll
            for (int j = 0; j < 8; ++j) v[j] = acc[i][j];
            if constexpr (MODE == 2) {
                #pragma unroll
                for (int p = 0; p < 4; ++p) {
                    const int ip = (d0 >> 1) + p;      // rope pair index
                    const float invf = __expf(-0.28782313662425575f * (float)ip);
                    const float ang = (float)pos * invf;
                    float sn, cs;
                    sincosf(ang, &sn, &cs);
                    const float xe = v[2 * p], xo = v[2 * p + 1];
                    v[2 * p]     = xe * cs - xo * sn;
                    v[2 * p + 1] = xe * sn + xo * cs;
                }
            }
            float* orow = out + (((size_t)bidx * H_ + hh) * S_ + pos) * DH_ + d0;
            *reinterpret_cast<float4*>(orow) = make_float4(v[0], v[1], v[2], v[3]);
            *reinterpret_cast<float4*>(orow + 4) = make_float4(v[4], v[5], v[6], v[7]);
        }
    } else { // MODE 4
        #pragma unroll
        for (int i = 0; i < 8; ++i) {
            const size_t off = (size_t)(r0 + i) * N + c0;
            const float4 ra = *reinterpret_cast<const float4*>(res + off);
            const float4 rb = *reinterpret_cast<const float4*>(res + off + 4);
            *reinterpret_cast<float4*>(out + off) =
                make_float4(acc[i][0] + ra.x, acc[i][1] + ra.y, acc[i][2] + ra.z, acc[i][3] + ra.w);
            *reinterpret_cast<float4*>(out + off + 4) =
                make_float4(acc[i][4] + rb.x, acc[i][5] + rb.y, acc[i][6] + rb.z, acc[i][7] + rb.w);
        }
    }
}

// ---------------------------------------------------------------------------
// Flash attention, fp32. One wave (64 threads) per 64 queries of one (b,h).
// Q/K/V in (b*H+h, s, d) layout. Output scattered to (b, s, h*64+d) layout.
// MASKMODE 0: attend t<=qi (causal incl. diag)
// MASKMODE 1: attend t<qi, plus (0,0)
// ---------------------------------------------------------------------------
template<int MASKMODE>
__global__ __launch_bounds__(64)
void flash_f32(const float* __restrict__ Qp, const float* __restrict__ Kp,
               const float* __restrict__ Vp, float* __restrict__ O)
{
    __shared__ float sK[32][64];
    __shared__ float sV[32][64];
    const int lane = threadIdx.x;
    const int qb = blockIdx.x;
    const int bh = blockIdx.y;
    const int qi = qb * 64 + lane;
    const float* qrow = Qp + ((size_t)bh * S_ + qi) * DH_;
    float q[64], o[64];
    #pragma unroll
    for (int i = 0; i < 16; ++i) {
        const float4 t = reinterpret_cast<const float4*>(qrow)[i];
        q[4 * i] = t.x; q[4 * i + 1] = t.y; q[4 * i + 2] = t.z; q[4 * i + 3] = t.w;
    }
    #pragma unroll
    for (int d = 0; d < 64; ++d) o[d] = 0.f;
    float m = -1e30f, l = 0.f;
    const int ntiles = 2 * qb + 2;
    for (int tile = 0; tile < ntiles; ++tile) {
        const int t0 = tile * 32;
        #pragma unroll
        for (int ii = 0; ii < 8; ++ii) {
            const int idx = ii * 64 + lane;
            const int row = idx >> 4;
            const int c4 = idx & 15;
            const size_t src = ((size_t)bh * S_ + t0 + row) * DH_;
            reinterpret_cast<float4*>(&sK[row][0])[c4] =
                reinterpret_cast<const float4*>(Kp + src)[c4];
            reinterpret_cast<float4*>(&sV[row][0])[c4] =
                reinterpret_cast<const float4*>(Vp + src)[c4];
        }
        __syncthreads();
        float pj[32];
        float tmax = -1e30f;
        #pragma unroll
        for (int j = 0; j < 32; ++j) {
            const int t = t0 + j;
            float s = 0.f;
            #pragma unroll
            for (int d4 = 0; d4 < 16; ++d4) {
                const float4 kv = reinterpret_cast<const float4*>(&sK[j][0])[d4];
                s = fmaf(q[4 * d4], kv.x, s);
                s = fmaf(q[4 * d4 + 1], kv.y, s);
                s = fmaf(q[4 * d4 + 2], kv.z, s);
                s = fmaf(q[4 * d4 + 3], kv.w, s);
            }
            bool valid;
            if (MASKMODE == 0) valid = (t <= qi);
            else valid = (t < qi) || (qi == 0 && t == 0);
            s = valid ? s * SCALE_ : -1e30f;
            pj[j] = s;
            tmax = fmaxf(tmax, s);
        }
        const float newm = fmaxf(m, tmax);
        if (newm > -0.9e30f) {
            const float alpha = __expf(m - newm);
            float psum = 0.f;
            #pragma unroll
            for (int j = 0; j < 32; ++j) {
                const float p = __expf(pj[j] - newm);
                pj[j] = p;
                psum += p;
            }
            l = l * alpha + psum;
            #pragma unroll
            for (int d = 0; d < 64; ++d) o[d] *= alpha;
            #pragma unroll
            for (int j = 0; j < 32; ++j) {
                const float p = pj[j];
                #pragma unroll
                for (int d4 = 0; d4 < 16; ++d4) {
                    const float4 vv = reinterpret_cast<const float4*>(&sV[j][0])[d4];
                    o[4 * d4]     = fmaf(p, vv.x, o[4 * d4]);
                    o[4 * d4 + 1] = fmaf(p, vv.y, o[4 * d4 + 1]);
                    o[4 * d4 + 2] = fmaf(p, vv.z, o[4 * d4 + 2]);
                    o[4 * d4 + 3] = fmaf(p, vv.w, o[4 * d4 + 3]);
                }
            }
            m = newm;
        }
        __syncthreads();
    }
    const float inv = 1.0f / l;
    const int b = bh >> 3, h = bh & 7;
    float* orow = O + ((size_t)b * S_ + qi) * DA_ + h * DH_;
    #pragma unroll
    for (int d4 = 0; d4 < 16; ++d4) {
        reinterpret_cast<float4*>(orow)[d4] =
            make_float4(o[4 * d4] * inv, o[4 * d4 + 1] * inv,
                        o[4 * d4 + 2] * inv, o[4 * d4 + 3] * inv);
    }
}

// ---------------------------------------------------------------------------
extern "C" void kernel_launch(void* const* d_in, const int* in_sizes, int n_in,
                              void* d_out, int out_size, void* d_ws, size_t ws_size,
                              hipStream_t stream)
{
    const float* cov_in  = (const float*)d_in[0];
    const float* tgt_in  = (const float*)d_in[1];
    const float* fu_in   = (const float*)d_in[2];
    const float* fc1w    = (const float*)d_in[3];
    const float* fc1b    = (const float*)d_in[4];
    const float* fc2w    = (const float*)d_in[5];
    const float* fc2b    = (const float*)d_in[6];
    const float* icl_wq  = (const float*)d_in[7];
    const float* icl_wk  = (const float*)d_in[8];
    const float* icl_wv  = (const float*)d_in[9];
    const float* icl_wo  = (const float*)d_in[10];
    const float* cov_wq  = (const float*)d_in[11];
    const float* cov_wk  = (const float*)d_in[12];
    const float* cov_wv  = (const float*)d_in[13];
    const float* cov_wo  = (const float*)d_in[14];
    const float* ln_cm_g = (const float*)d_in[15];
    const float* ln_cm_b = (const float*)d_in[16];
    const float* ln_ia_g = (const float*)d_in[17];
    const float* ln_ia_b = (const float*)d_in[18];
    const float* ln_im_g = (const float*)d_in[19];
    const float* ln_im_b = (const float*)d_in[20];

    const size_t NTOK = (size_t)B_ * S_;          // 4096
    float* out_cov = (float*)d_out;
    float* out_tgt = out_cov + NTOK * E_;
    float* out_fu  = out_tgt + NTOK * E_;

    // Workspace: 8M floats (32 MiB) main region + 16K floats stats = 32.06 MiB.
    float* ws    = (float*)d_ws;
    float* bufH  = ws;                             // 4096*2048 (MLP hidden)
    float* bufP  = ws;                             // 4096*512  (reuse after MLPs)
    float* bufK  = ws + NTOK * DA_;                // 4096*512
    float* bufV  = ws + 2 * NTOK * DA_;            // 4096*512
    float* bufO  = ws + 3 * NTOK * DA_;            // 4096*512
    float* stM   = ws + NTOK * DMLP_;              // 4096*2 (MLP LN stats)
    float* stIA  = stM + 2 * NTOK;                 // 4096*2 (ia LN stats)

    const int M = (int)NTOK;
    const dim3 blk(256);
    const dim3 stGrid(M);
    const dim3 fc1Grid(DMLP_ / GBN, M / GBM);
    const dim3 fc2Grid(E_ / GBN, M / GBM);
    const dim3 projGrid(DA_ / GBN, M / GBM);
    const dim3 oprjGrid(E_ / GBN, M / GBM);
    const dim3 flashGrid(S_ / 64, B_ * H_);

    // --- cov = covariates + MLP(LN_cm(covariates)) ---
    ln_stats<<<stGrid, blk, 0, stream>>>(cov_in, stM);
    gemm_f32<0, true><<<fc1Grid, blk, 0, stream>>>(cov_in, fc1w, fc1b, nullptr, bufH,
                                                   stM, ln_cm_g, ln_cm_b, M, DMLP_, E_);
    gemm_f32<1, false><<<fc2Grid, blk, 0, stream>>>(bufH, fc2w, fc2b, cov_in, out_cov,
                                                    nullptr, nullptr, nullptr, M, E_, DMLP_);

    // --- tgt = targets + MLP(LN_im(functional_update)) ---
    ln_stats<<<stGrid, blk, 0, stream>>>(fu_in, stM);
    gemm_f32<0, true><<<fc1Grid, blk, 0, stream>>>(fu_in, fc1w, fc1b, nullptr, bufH,
                                                   stM, ln_im_g, ln_im_b, M, DMLP_, E_);
    gemm_f32<1, false><<<fc2Grid, blk, 0, stream>>>(bufH, fc2w, fc2b, tgt_in, out_tgt,
                                                    nullptr, nullptr, nullptr, M, E_, DMLP_);

    // --- q = LN_ia(cov) applied on the fly via stIA ---
    ln_stats<<<stGrid, blk, 0, stream>>>(out_cov, stIA);

    // --- attn 1 (icl): fu = functional_update + attn(q, q, tgt) ---
    gemm_f32<2, true><<<projGrid, blk, 0, stream>>>(out_cov, icl_wq, nullptr, nullptr, bufP,
                                                    stIA, ln_ia_g, ln_ia_b, M, DA_, E_);
    gemm_f32<2, true><<<projGrid, blk, 0, stream>>>(out_cov, icl_wk, nullptr, nullptr, bufK,
                                                    stIA, ln_ia_g, ln_ia_b, M, DA_, E_);
    gemm_f32<3, false><<<projGrid, blk, 0, stream>>>(out_tgt, icl_wv, nullptr, nullptr, bufV,
                                                     nullptr, nullptr, nullptr, M, DA_, E_);
    flash_f32<1><<<flashGrid, dim3(64), 0, stream>>>(bufP, bufK, bufV, bufO);
    gemm_f32<4, false><<<oprjGrid, blk, 0, stream>>>(bufO, icl_wo, nullptr, fu_in, out_fu,
                                                     nullptr, nullptr, nullptr, M, E_, DA_);

    // --- attn 2 (cov): cov = cov + attn(q, q, q) ---
    gemm_f32<2, true><<<projGrid, blk, 0, stream>>>(out_cov, cov_wq, nullptr, nullptr, bufP,
                                                    stIA, ln_ia_g, ln_ia_b, M, DA_, E_);
    gemm_f32<2, true><<<projGrid, blk, 0, stream>>>(out_cov, cov_wk, nullptr, nullptr, bufK,
                                                    stIA, ln_ia_g, ln_ia_b, M, DA_, E_);
    gemm_f32<3, true><<<projGrid, blk, 0, stream>>>(out_cov, cov_wv, nullptr, nullptr, bufV,
                                                    stIA, ln_ia_g, ln_ia_b, M, DA_, E_);
    flash_f32<0><<<flashGrid, dim3(64), 0, stream>>>(bufP, bufK, bufV, bufO);
    gemm_f32<4, false><<<oprjGrid, blk, 0, stream>>>(bufO, cov_wo, nullptr, out_cov, out_cov,
                                                     nullptr, nullptr, nullptr, M, E_, DA_);
}

// Round 4
// 1909.112 us; speedup vs baseline: 2.4882x; 2.4882x over previous
//
#include <hip/hip_runtime.h>
#include <math.h>

#define B_ 2
#define S_ 2048
#define E_ 1024
#define H_ 8
#define DH_ 64
#define DA_ 512
#define DMLP_ 2048
#define SCALE_ 0.04419417382415922f   // 1/sqrt(512)
#define LN_EPS_ 1e-5f
#define ROPE_C_ 0.28782313662425575f  // ln(10000)/32

typedef short  s16x8 __attribute__((ext_vector_type(8)));
typedef short  s16x4 __attribute__((ext_vector_type(4)));
typedef unsigned short u16x8 __attribute__((ext_vector_type(8)));
typedef float  f32x4 __attribute__((ext_vector_type(4)));

static __device__ __forceinline__ float bf2f(unsigned short u) {
    unsigned int x = ((unsigned int)u) << 16;
    return __builtin_bit_cast(float, x);
}
static __device__ __forceinline__ unsigned short f2bf(float f) {
    unsigned int x = __builtin_bit_cast(unsigned int, f);
    x += 0x7fffu + ((x >> 16) & 1u);
    return (unsigned short)(x >> 16);
}

// ---------------------------------------------------------------------------
// Per-row LN stats: stats[2*row]=mean, stats[2*row+1]=rsqrt(var+eps).
// ---------------------------------------------------------------------------
__global__ __launch_bounds__(256)
void ln_stats(const float* __restrict__ x, float* __restrict__ stats)
{
    __shared__ float sm[8];
    const int row = blockIdx.x;
    const int tid = threadIdx.x;
    const float4 v = reinterpret_cast<const float4*>(x + (size_t)row * E_)[tid];
    float s = v.x + v.y + v.z + v.w;
    float q = v.x * v.x + v.y * v.y + v.z * v.z + v.w * v.w;
    #pragma unroll
    for (int o = 32; o > 0; o >>= 1) {
        s += __shfl_down(s, o);
        q += __shfl_down(q, o);
    }
    const int wid = tid >> 6, lane = tid & 63;
    if (lane == 0) { sm[wid] = s; sm[4 + wid] = q; }
    __syncthreads();
    if (tid == 0) {
        const float ts = sm[0] + sm[1] + sm[2] + sm[3];
        const float tq = sm[4] + sm[5] + sm[6] + sm[7];
        const float mu = ts * (1.0f / E_);
        const float var = tq * (1.0f / E_) - mu * mu;
        stats[2 * row]     = mu;
        stats[2 * row + 1] = rsqrtf(var + LN_EPS_);
    }
}

// ---------------------------------------------------------------------------
// Weight transpose + bf16 convert: W [K][N] f32 -> WT [N][K] bf16.
// 64x64 tiles via LDS. grid = (N/64, K/64), 256 threads.
// ---------------------------------------------------------------------------
__global__ __launch_bounds__(256)
void wt_cvt(const float* __restrict__ W, unsigned short* __restrict__ WT, int K, int N)
{
    __shared__ float sm[64][65];
    const int n0 = blockIdx.x * 64;
    const int k0 = blockIdx.y * 64;
    const int t = threadIdx.x;
    const int kr = t >> 2;
    const int nc = (t & 3) * 16;
    #pragma unroll
    for (int i = 0; i < 4; ++i) {
        const float4 v = *reinterpret_cast<const float4*>(W + (size_t)(k0 + kr) * N + n0 + nc + 4 * i);
        sm[kr][nc + 4 * i + 0] = v.x;
        sm[kr][nc + 4 * i + 1] = v.y;
        sm[kr][nc + 4 * i + 2] = v.z;
        sm[kr][nc + 4 * i + 3] = v.w;
    }
    __syncthreads();
    const int nr = t >> 2;
    const int kc = (t & 3) * 16;
    u16x8 a, b;
    #pragma unroll
    for (int i = 0; i < 8; ++i) a[i] = f2bf(sm[kc + i][nr]);
    #pragma unroll
    for (int i = 0; i < 8; ++i) b[i] = f2bf(sm[kc + 8 + i][nr]);
    unsigned short* dst = WT + (size_t)(n0 + nr) * K + k0 + kc;
    *reinterpret_cast<u16x8*>(dst)     = a;
    *reinterpret_cast<u16x8*>(dst + 8) = b;
}

// ---------------------------------------------------------------------------
// bf16 MFMA GEMM: out = epilogue(op(A) @ W),  W given pre-transposed bf16
// WT [N][K].  A: [M][K] f32 (AMODE 0/1) or bf16 (AMODE 2).
// 128x128 tile, BK=32, 256 thr = 4 waves, each wave 64x64 via 4x4 MFMA tiles.
// MODE 0: +bias, exact gelu, bf16 row-major out          (fc1 -> H)
// MODE 1: +bias, +res, f32 row-major out                 (fc2)
// MODE 2: RoPE + scatter bf16 to (b,h,s,d)               (q/k proj)
// MODE 3: scatter bf16 to (b,h,s,d)                      (v proj)
// MODE 4: +res, f32 row-major out                        (attn out proj)
// AMODE 0: A f32;  1: A f32 + LN(stats,g,b);  2: A bf16
// ---------------------------------------------------------------------------
#define RS 40   // LDS row stride in bf16 elems (80 B, 16B-aligned, <=2-way banks)

template<int MODE, int AMODE>
__global__ __launch_bounds__(256)
void gemm_mfma(const void* __restrict__ Ap, const unsigned short* __restrict__ WT,
               const float* __restrict__ bias, const float* res, void* outp,
               const float* __restrict__ stats, const float* __restrict__ lng,
               const float* __restrict__ lnb, int M, int N, int K)
{
    __shared__ unsigned short sA[128 * RS];
    __shared__ unsigned short sB[128 * RS];
    const int tid  = threadIdx.x;
    const int lane = tid & 63;
    const int w    = tid >> 6;
    const int wr   = w >> 1, wc = w & 1;
    const int bm   = blockIdx.y * 128;
    const int bn   = blockIdx.x * 128;
    const int lr   = lane & 15;
    const int kb   = lane >> 4;

    f32x4 acc[4][4];
    #pragma unroll
    for (int i = 0; i < 4; ++i)
        #pragma unroll
        for (int j = 0; j < 4; ++j)
            acc[i][j] = f32x4{0.f, 0.f, 0.f, 0.f};

    // fp32-A staging geometry
    const int arow  = tid >> 1;
    const int akoff = (tid & 1) * 16;
    float amu = 0.f, ars = 0.f;
    if constexpr (AMODE == 1) {
        amu = stats[2 * (bm + arow)];
        ars = stats[2 * (bm + arow) + 1];
    }

    for (int k0 = 0; k0 < K; k0 += 32) {
        // ---- stage A ----
        if constexpr (AMODE <= 1) {
            const float* Arow = (const float*)Ap + (size_t)(bm + arow) * K + k0 + akoff;
            float vals[16];
            #pragma unroll
            for (int i = 0; i < 4; ++i) {
                const float4 a4 = *reinterpret_cast<const float4*>(Arow + 4 * i);
                vals[4 * i + 0] = a4.x; vals[4 * i + 1] = a4.y;
                vals[4 * i + 2] = a4.z; vals[4 * i + 3] = a4.w;
            }
            if constexpr (AMODE == 1) {
                #pragma unroll
                for (int i = 0; i < 4; ++i) {
                    const float4 g4 = *reinterpret_cast<const float4*>(lng + k0 + akoff + 4 * i);
                    const float4 b4 = *reinterpret_cast<const float4*>(lnb + k0 + akoff + 4 * i);
                    vals[4 * i + 0] = (vals[4 * i + 0] - amu) * ars * g4.x + b4.x;
                    vals[4 * i + 1] = (vals[4 * i + 1] - amu) * ars * g4.y + b4.y;
                    vals[4 * i + 2] = (vals[4 * i + 2] - amu) * ars * g4.z + b4.z;
                    vals[4 * i + 3] = (vals[4 * i + 3] - amu) * ars * g4.w + b4.w;
                }
            }
            #pragma unroll
            for (int i = 0; i < 4; ++i) {
                s16x4 p;
                p[0] = (short)f2bf(vals[4 * i + 0]);
                p[1] = (short)f2bf(vals[4 * i + 1]);
                p[2] = (short)f2bf(vals[4 * i + 2]);
                p[3] = (short)f2bf(vals[4 * i + 3]);
                *reinterpret_cast<s16x4*>(&sA[arow * RS + akoff + 4 * i]) = p;
            }
        } else {
            #pragma unroll
            for (int cc = 0; cc < 2; ++cc) {
                const int c = tid + cc * 256;
                const int row = c >> 2, q = c & 3;
                const u16x8 v = *reinterpret_cast<const u16x8*>(
                    (const unsigned short*)Ap + (size_t)(bm + row) * K + k0 + q * 8);
                *reinterpret_cast<u16x8*>(&sA[row * RS + q * 8]) = v;
            }
        }
        // ---- stage B (always bf16 WT) ----
        #pragma unroll
        for (int cc = 0; cc < 2; ++cc) {
            const int c = tid + cc * 256;
            const int row = c >> 2, q = c & 3;
            const u16x8 v = *reinterpret_cast<const u16x8*>(
                WT + (size_t)(bn + row) * K + k0 + q * 8);
            *reinterpret_cast<u16x8*>(&sB[row * RS + q * 8]) = v;
        }
        __syncthreads();

        s16x8 af[4], bfr[4];
        #pragma unroll
        for (int i = 0; i < 4; ++i) {
            af[i]  = *reinterpret_cast<const s16x8*>(&sA[(wr * 64 + i * 16 + lr) * RS + kb * 8]);
            bfr[i] = *reinterpret_cast<const s16x8*>(&sB[(wc * 64 + i * 16 + lr) * RS + kb * 8]);
        }
        #pragma unroll
        for (int mt = 0; mt < 4; ++mt)
            #pragma unroll
            for (int nt = 0; nt < 4; ++nt)
                acc[mt][nt] = __builtin_amdgcn_mfma_f32_16x16x32_bf16(
                    af[mt], bfr[nt], acc[mt][nt], 0, 0, 0);
        __syncthreads();
    }

    // ---- epilogue ----
    const int le = lane >> 4;    // C/D: col = lane&15, row = (lane>>4)*4 + e

    if constexpr (MODE == 0 || MODE == 1 || MODE == 4) {
        float bcol[4];
        #pragma unroll
        for (int nt = 0; nt < 4; ++nt)
            bcol[nt] = (MODE == 4) ? 0.f : bias[bn + wc * 64 + nt * 16 + lr];
        #pragma unroll
        for (int mt = 0; mt < 4; ++mt)
            #pragma unroll
            for (int e = 0; e < 4; ++e) {
                const int row = bm + wr * 64 + mt * 16 + le * 4 + e;
                #pragma unroll
                for (int nt = 0; nt < 4; ++nt) {
                    const int col = bn + wc * 64 + nt * 16 + lr;
                    const size_t off = (size_t)row * N + col;
                    float v = acc[mt][nt][e] + bcol[nt];
                    if constexpr (MODE == 0) {
                        v = 0.5f * v * (1.0f + erff(v * 0.70710678118654752f));
                        ((unsigned short*)outp)[off] = f2bf(v);
                    } else {
                        v += res[off];
                        ((float*)outp)[off] = v;
                    }
                }
            }
    } else {  // MODE 2 / 3: scatter to (b,h,s,d) bf16, optional RoPE
        float invfr[4];
        #pragma unroll
        for (int nt = 0; nt < 4; ++nt)
            invfr[nt] = __expf(-ROPE_C_ * (float)((nt * 16 + lr) >> 1));
        #pragma unroll
        for (int mt = 0; mt < 4; ++mt)
            #pragma unroll
            for (int e = 0; e < 4; ++e) {
                const int row  = bm + wr * 64 + mt * 16 + le * 4 + e;
                const int pos  = row & (S_ - 1);
                const int bidx = row >> 11;
                #pragma unroll
                for (int nt = 0; nt < 4; ++nt) {
                    const int col = bn + wc * 64 + nt * 16 + lr;
                    float val = acc[mt][nt][e];
                    float outv = val;
                    if constexpr (MODE == 2) {
                        const float pv = __shfl_xor(val, 1);
                        float sn, cs;
                        sincosf((float)pos * invfr[nt], &sn, &cs);
                        outv = ((lr & 1) == 0) ? (val * cs - pv * sn)
                                               : (pv * sn + val * cs);
                    }
                    const int hh = col >> 6, d = col & 63;
                    ((unsigned short*)outp)[(((size_t)bidx * H_ + hh) * S_ + pos) * DH_ + d]
                        = f2bf(outv);
                }
            }
    }
}

// ---------------------------------------------------------------------------
// Flash attention, bf16 in / bf16 out, fp32 compute.
// One wave per 16 queries: lane = q4*4 + part; part owns 16 of 64 dims.
// Q/K/V bf16 in (b*H+h, s, d); O bf16 scattered to (b, s, h*64+d).
// MASKMODE 0: attend t<=qi ;  1: attend t<qi plus (0,0)
// ---------------------------------------------------------------------------
template<int MASKMODE>
__global__ __launch_bounds__(64)
void flash_bf16(const unsigned short* __restrict__ Qp, const unsigned short* __restrict__ Kp,
                const unsigned short* __restrict__ Vp, unsigned short* __restrict__ O)
{
    __shared__ float sK[32][64];
    __shared__ float sV[32][64];
    const int lane = threadIdx.x;
    const int part = lane & 3;
    const int q4   = lane >> 2;
    const int qb   = blockIdx.x;
    const int bh   = blockIdx.y;
    const int qi   = qb * 16 + q4;

    float q[16], o[16];
    {
        const unsigned short* qrow = Qp + ((size_t)bh * S_ + qi) * DH_ + part * 16;
        #pragma unroll
        for (int i = 0; i < 2; ++i) {
            const u16x8 v = *reinterpret_cast<const u16x8*>(qrow + 8 * i);
            #pragma unroll
            for (int j = 0; j < 8; ++j) q[8 * i + j] = bf2f(v[j]);
        }
    }
    #pragma unroll
    for (int d = 0; d < 16; ++d) o[d] = 0.f;
    float m = -1e30f, l = 0.f;

    const int ntiles = (qb * 16 + 15) / 32 + 1;
    for (int tile = 0; tile < ntiles; ++tile) {
        const int t0 = tile * 32;
        #pragma unroll
        for (int it = 0; it < 4; ++it) {
            const int c = it * 64 + lane;          // 0..255
            const int row = c >> 3, col8 = (c & 7) * 8;
            const size_t src = ((size_t)bh * S_ + t0 + row) * DH_ + col8;
            const u16x8 kv = *reinterpret_cast<const u16x8*>(Kp + src);
            const u16x8 vv = *reinterpret_cast<const u16x8*>(Vp + src);
            float kf[8], vf[8];
            #pragma unroll
            for (int j = 0; j < 8; ++j) { kf[j] = bf2f(kv[j]); vf[j] = bf2f(vv[j]); }
            *reinterpret_cast<float4*>(&sK[row][col8])     = make_float4(kf[0], kf[1], kf[2], kf[3]);
            *reinterpret_cast<float4*>(&sK[row][col8 + 4]) = make_float4(kf[4], kf[5], kf[6], kf[7]);
            *reinterpret_cast<float4*>(&sV[row][col8])     = make_float4(vf[0], vf[1], vf[2], vf[3]);
            *reinterpret_cast<float4*>(&sV[row][col8 + 4]) = make_float4(vf[4], vf[5], vf[6], vf[7]);
        }
        __syncthreads();

        float pj[32];
        float tmax = -1e30f;
        #pragma unroll
        for (int j = 0; j < 32; ++j) {
            const float4* kr = reinterpret_cast<const float4*>(&sK[j][part * 16]);
            float s = 0.f;
            #pragma unroll
            for (int c4 = 0; c4 < 4; ++c4) {
                const float4 kv = kr[c4];
                s = fmaf(q[4 * c4 + 0], kv.x, s);
                s = fmaf(q[4 * c4 + 1], kv.y, s);
                s = fmaf(q[4 * c4 + 2], kv.z, s);
                s = fmaf(q[4 * c4 + 3], kv.w, s);
            }
            s += __shfl_xor(s, 1);
            s += __shfl_xor(s, 2);
            const int t = t0 + j;
            bool valid;
            if (MASKMODE == 0) valid = (t <= qi);
            else               valid = (t < qi) || (qi == 0 && t == 0);
            s = valid ? s * SCALE_ : -1e30f;
            pj[j] = s;
            tmax = fmaxf(tmax, s);
        }
        const float newm = fmaxf(m, tmax);
        if (newm > -0.9e30f) {
            const float alpha = __expf(m - newm);
            float psum = 0.f;
            #pragma unroll
            for (int j = 0; j < 32; ++j) {
                const float p = __expf(pj[j] - newm);
                pj[j] = p;
                psum += p;
            }
            l = l * alpha + psum;
            #pragma unroll
            for (int d = 0; d < 16; ++d) o[d] *= alpha;
            #pragma unroll
            for (int j = 0; j < 32; ++j) {
                const float p = pj[j];
                const float4* vr = reinterpret_cast<const float4*>(&sV[j][part * 16]);
                #pragma unroll
                for (int c4 = 0; c4 < 4; ++c4) {
                    const float4 vv = vr[c4];
                    o[4 * c4 + 0] = fmaf(p, vv.x, o[4 * c4 + 0]);
                    o[4 * c4 + 1] = fmaf(p, vv.y, o[4 * c4 + 1]);
                    o[4 * c4 + 2] = fmaf(p, vv.z, o[4 * c4 + 2]);
                    o[4 * c4 + 3] = fmaf(p, vv.w, o[4 * c4 + 3]);
                }
            }
            m = newm;
        }
        __syncthreads();
    }

    const float inv = 1.0f / l;
    const int b = bh >> 3, h = bh & 7;
    unsigned short* orow = O + ((size_t)b * S_ + qi) * DA_ + h * DH_ + part * 16;
    u16x8 w0, w1;
    #pragma unroll
    for (int j = 0; j < 8; ++j) w0[j] = f2bf(o[j] * inv);
    #pragma unroll
    for (int j = 0; j < 8; ++j) w1[j] = f2bf(o[8 + j] * inv);
    *reinterpret_cast<u16x8*>(orow)     = w0;
    *reinterpret_cast<u16x8*>(orow + 8) = w1;
}

// ---------------------------------------------------------------------------
extern "C" void kernel_launch(void* const* d_in, const int* in_sizes, int n_in,
                              void* d_out, int out_size, void* d_ws, size_t ws_size,
                              hipStream_t stream)
{
    const float* cov_in  = (const float*)d_in[0];
    const float* tgt_in  = (const float*)d_in[1];
    const float* fu_in   = (const float*)d_in[2];
    const float* fc1w    = (const float*)d_in[3];
    const float* fc1b    = (const float*)d_in[4];
    const float* fc2w    = (const float*)d_in[5];
    const float* fc2b    = (const float*)d_in[6];
    const float* icl_wq  = (const float*)d_in[7];
    const float* icl_wk  = (const float*)d_in[8];
    const float* icl_wv  = (const float*)d_in[9];
    const float* icl_wo  = (const float*)d_in[10];
    const float* cov_wq  = (const float*)d_in[11];
    const float* cov_wk  = (const float*)d_in[12];
    const float* cov_wv  = (const float*)d_in[13];
    const float* cov_wo  = (const float*)d_in[14];
    const float* ln_cm_g = (const float*)d_in[15];
    const float* ln_cm_b = (const float*)d_in[16];
    const float* ln_ia_g = (const float*)d_in[17];
    const float* ln_ia_b = (const float*)d_in[18];
    const float* ln_im_g = (const float*)d_in[19];
    const float* ln_im_b = (const float*)d_in[20];

    const size_t NTOK = (size_t)B_ * S_;          // 4096
    float* out_cov = (float*)d_out;
    float* out_tgt = out_cov + NTOK * E_;
    float* out_fu  = out_tgt + NTOK * E_;

    // Workspace (32 MiB + 64 KiB total — same footprint as the passing run):
    //   [0,16MiB):  H bf16 during MLPs; later P/K/V/O bf16 (4 MiB each)
    //   [16,32MiB): bf16 transposed weights
    //   [32MiB, +64KiB): LN stats
    unsigned short* wsb = (unsigned short*)d_ws;
    unsigned short* H16 = wsb;
    unsigned short* P16 = wsb;
    unsigned short* K16 = wsb + 2u * 1024 * 1024;
    unsigned short* V16 = wsb + 4u * 1024 * 1024;
    unsigned short* O16 = wsb + 6u * 1024 * 1024;
    unsigned short* wT  = wsb + 8u * 1024 * 1024;
    unsigned short* fc1wT   = wT;                        // 2M elems
    unsigned short* fc2wT   = wT + 2u * 1024 * 1024;     // 2M
    unsigned short* icl_wqT = wT + 4u * 1024 * 1024;     // 0.5M each
    unsigned short* icl_wkT = icl_wqT + 512u * 1024;
    unsigned short* icl_wvT = icl_wkT + 512u * 1024;
    unsigned short* icl_woT = icl_wvT + 512u * 1024;
    unsigned short* cov_wqT = icl_woT + 512u * 1024;
    unsigned short* cov_wkT = cov_wqT + 512u * 1024;
    unsigned short* cov_wvT = cov_wkT + 512u * 1024;
    unsigned short* cov_woT = cov_wvT + 512u * 1024;
    float* stM  = (float*)(wsb + 16u * 1024 * 1024);
    float* stIA = stM + 2 * NTOK;

    const int M = (int)NTOK;
    const dim3 blk(256);

    // --- weight transpose + bf16 convert (10 matrices) ---
    wt_cvt<<<dim3(DMLP_ / 64, E_ / 64), blk, 0, stream>>>(fc1w, fc1wT, E_, DMLP_);
    wt_cvt<<<dim3(E_ / 64, DMLP_ / 64), blk, 0, stream>>>(fc2w, fc2wT, DMLP_, E_);
    wt_cvt<<<dim3(DA_ / 64, E_ / 64), blk, 0, stream>>>(icl_wq, icl_wqT, E_, DA_);
    wt_cvt<<<dim3(DA_ / 64, E_ / 64), blk, 0, stream>>>(icl_wk, icl_wkT, E_, DA_);
    wt_cvt<<<dim3(DA_ / 64, E_ / 64), blk, 0, stream>>>(icl_wv, icl_wvT, E_, DA_);
    wt_cvt<<<dim3(E_ / 64, DA_ / 64), blk, 0, stream>>>(icl_wo, icl_woT, DA_, E_);
    wt_cvt<<<dim3(DA_ / 64, E_ / 64), blk, 0, stream>>>(cov_wq, cov_wqT, E_, DA_);
    wt_cvt<<<dim3(DA_ / 64, E_ / 64), blk, 0, stream>>>(cov_wk, cov_wkT, E_, DA_);
    wt_cvt<<<dim3(DA_ / 64, E_ / 64), blk, 0, stream>>>(cov_wv, cov_wvT, E_, DA_);
    wt_cvt<<<dim3(E_ / 64, DA_ / 64), blk, 0, stream>>>(cov_wo, cov_woT, DA_, E_);

    const dim3 fc1Grid(DMLP_ / 128, M / 128);
    const dim3 fc2Grid(E_ / 128, M / 128);
    const dim3 projGrid(DA_ / 128, M / 128);
    const dim3 oprjGrid(E_ / 128, M / 128);
    const dim3 flashGrid(S_ / 16, B_ * H_);

    // --- cov = covariates + MLP(LN_cm(covariates)) ---
    ln_stats<<<dim3(M), blk, 0, stream>>>(cov_in, stM);
    gemm_mfma<0, 1><<<fc1Grid, blk, 0, stream>>>(cov_in, fc1wT, fc1b, nullptr, H16,
                                                 stM, ln_cm_g, ln_cm_b, M, DMLP_, E_);
    gemm_mfma<1, 2><<<fc2Grid, blk, 0, stream>>>(H16, fc2wT, fc2b, cov_in, out_cov,
                                                 nullptr, nullptr, nullptr, M, E_, DMLP_);

    // --- tgt = targets + MLP(LN_im(functional_update)) ---
    ln_stats<<<dim3(M), blk, 0, stream>>>(fu_in, stM);
    gemm_mfma<0, 1><<<fc1Grid, blk, 0, stream>>>(fu_in, fc1wT, fc1b, nullptr, H16,
                                                 stM, ln_im_g, ln_im_b, M, DMLP_, E_);
    gemm_mfma<1, 2><<<fc2Grid, blk, 0, stream>>>(H16, fc2wT, fc2b, tgt_in, out_tgt,
                                                 nullptr, nullptr, nullptr, M, E_, DMLP_);

    // --- q = LN_ia(cov), applied on the fly ---
    ln_stats<<<dim3(M), blk, 0, stream>>>(out_cov, stIA);

    // --- attn 1 (icl): fu = functional_update + attn(q, q, tgt) ---
    gemm_mfma<2, 1><<<projGrid, blk, 0, stream>>>(out_cov, icl_wqT, nullptr, nullptr, P16,
                                                  stIA, ln_ia_g, ln_ia_b, M, DA_, E_);
    gemm_mfma<2, 1><<<projGrid, blk, 0, stream>>>(out_cov, icl_wkT, nullptr, nullptr, K16,
                                                  stIA, ln_ia_g, ln_ia_b, M, DA_, E_);
    gemm_mfma<3, 0><<<projGrid, blk, 0, stream>>>(out_tgt, icl_wvT, nullptr, nullptr, V16,
                                                  nullptr, nullptr, nullptr, M, DA_, E_);
    flash_bf16<1><<<flashGrid, dim3(64), 0, stream>>>(P16, K16, V16, O16);
    gemm_mfma<4, 2><<<oprjGrid, blk, 0, stream>>>(O16, icl_woT, nullptr, fu_in, out_fu,
                                                  nullptr, nullptr, nullptr, M, E_, DA_);

    // --- attn 2 (cov): cov = cov + attn(q, q, q) ---
    gemm_mfma<2, 1><<<projGrid, blk, 0, stream>>>(out_cov, cov_wqT, nullptr, nullptr, P16,
                                                  stIA, ln_ia_g, ln_ia_b, M, DA_, E_);
    gemm_mfma<2, 1><<<projGrid, blk, 0, stream>>>(out_cov, cov_wkT, nullptr, nullptr, K16,
                                                  stIA, ln_ia_g, ln_ia_b, M, DA_, E_);
    gemm_mfma<3, 1><<<projGrid, blk, 0, stream>>>(out_cov, cov_wvT, nullptr, nullptr, V16,
                                                  stIA, ln_ia_g, ln_ia_b, M, DA_, E_);
    flash_bf16<0><<<flashGrid, dim3(64), 0, stream>>>(P16, K16, V16, O16);
    gemm_mfma<4, 2><<<oprjGrid, blk, 0, stream>>>(O16, cov_woT, nullptr, out_cov, out_cov,
                                                  nullptr, nullptr, nullptr, M, E_, DA_);
}

// Round 5
// 1213.126 us; speedup vs baseline: 3.9157x; 1.5737x over previous
//
#include <hip/hip_runtime.h>
#include <math.h>

#define B_ 2
#define S_ 2048
#define E_ 1024
#define H_ 8
#define DH_ 64
#define DA_ 512
#define DMLP_ 2048
#define SCALE_ 0.04419417382415922f   // 1/sqrt(512)
#define LN_EPS_ 1e-5f
#define ROPE_C_ 0.28782313662425575f  // ln(10000)/32

typedef short  s16x8 __attribute__((ext_vector_type(8)));
typedef short  s16x4 __attribute__((ext_vector_type(4)));
typedef unsigned short u16x8 __attribute__((ext_vector_type(8)));
typedef unsigned short u16x4 __attribute__((ext_vector_type(4)));
typedef float  f32x4 __attribute__((ext_vector_type(4)));

static __device__ __forceinline__ float bf2f(unsigned short u) {
    unsigned int x = ((unsigned int)u) << 16;
    return __builtin_bit_cast(float, x);
}
static __device__ __forceinline__ unsigned short f2bf(float f) {
    unsigned int x = __builtin_bit_cast(unsigned int, f);
    x += 0x7fffu + ((x >> 16) & 1u);
    return (unsigned short)(x >> 16);
}

// ---------------------------------------------------------------------------
// Per-row LN stats: stats[2*row]=mean, stats[2*row+1]=rsqrt(var+eps).
// ---------------------------------------------------------------------------
__global__ __launch_bounds__(256)
void ln_stats(const float* __restrict__ x, float* __restrict__ stats)
{
    __shared__ float sm[8];
    const int row = blockIdx.x;
    const int tid = threadIdx.x;
    const float4 v = reinterpret_cast<const float4*>(x + (size_t)row * E_)[tid];
    float s = v.x + v.y + v.z + v.w;
    float q = v.x * v.x + v.y * v.y + v.z * v.z + v.w * v.w;
    #pragma unroll
    for (int o = 32; o > 0; o >>= 1) {
        s += __shfl_down(s, o);
        q += __shfl_down(q, o);
    }
    const int wid = tid >> 6, lane = tid & 63;
    if (lane == 0) { sm[wid] = s; sm[4 + wid] = q; }
    __syncthreads();
    if (tid == 0) {
        const float ts = sm[0] + sm[1] + sm[2] + sm[3];
        const float tq = sm[4] + sm[5] + sm[6] + sm[7];
        const float mu = ts * (1.0f / E_);
        const float var = tq * (1.0f / E_) - mu * mu;
        stats[2 * row]     = mu;
        stats[2 * row + 1] = rsqrtf(var + LN_EPS_);
    }
}

// ---------------------------------------------------------------------------
// Weight transpose + bf16 convert: W [K][N] f32 -> WT [N][K] bf16.
// ---------------------------------------------------------------------------
__global__ __launch_bounds__(256)
void wt_cvt(const float* __restrict__ W, unsigned short* __restrict__ WT, int K, int N)
{
    __shared__ float sm[64][65];
    const int n0 = blockIdx.x * 64;
    const int k0 = blockIdx.y * 64;
    const int t = threadIdx.x;
    const int kr = t >> 2;
    const int nc = (t & 3) * 16;
    #pragma unroll
    for (int i = 0; i < 4; ++i) {
        const float4 v = *reinterpret_cast<const float4*>(W + (size_t)(k0 + kr) * N + n0 + nc + 4 * i);
        sm[kr][nc + 4 * i + 0] = v.x;
        sm[kr][nc + 4 * i + 1] = v.y;
        sm[kr][nc + 4 * i + 2] = v.z;
        sm[kr][nc + 4 * i + 3] = v.w;
    }
    __syncthreads();
    const int nr = t >> 2;
    const int kc = (t & 3) * 16;
    u16x8 a, b;
    #pragma unroll
    for (int i = 0; i < 8; ++i) a[i] = f2bf(sm[kc + i][nr]);
    #pragma unroll
    for (int i = 0; i < 8; ++i) b[i] = f2bf(sm[kc + 8 + i][nr]);
    unsigned short* dst = WT + (size_t)(n0 + nr) * K + k0 + kc;
    *reinterpret_cast<u16x8*>(dst)     = a;
    *reinterpret_cast<u16x8*>(dst + 8) = b;
}

// ---------------------------------------------------------------------------
// bf16 MFMA GEMM (unchanged structure from round 4).
// MODE 0: +bias, gelu, bf16 out     MODE 1: +bias,+res f32 out
// MODE 2: RoPE, scatter (bh,s,d)    MODE 3: scatter V^T (bh,d,s)
// MODE 4: +res f32 out
// AMODE 0: A f32; 1: A f32+LN; 2: A bf16
// ---------------------------------------------------------------------------
#define RS 40

template<int MODE, int AMODE>
__global__ __launch_bounds__(256)
void gemm_mfma(const void* __restrict__ Ap, const unsigned short* __restrict__ WT,
               const float* __restrict__ bias, const float* res, void* outp,
               const float* __restrict__ stats, const float* __restrict__ lng,
               const float* __restrict__ lnb, int M, int N, int K)
{
    __shared__ unsigned short sA[128 * RS];
    __shared__ unsigned short sB[128 * RS];
    const int tid  = threadIdx.x;
    const int lane = tid & 63;
    const int w    = tid >> 6;
    const int wr   = w >> 1, wc = w & 1;
    const int bm   = blockIdx.y * 128;
    const int bn   = blockIdx.x * 128;
    const int lr   = lane & 15;
    const int kb   = lane >> 4;

    f32x4 acc[4][4];
    #pragma unroll
    for (int i = 0; i < 4; ++i)
        #pragma unroll
        for (int j = 0; j < 4; ++j)
            acc[i][j] = f32x4{0.f, 0.f, 0.f, 0.f};

    const int arow  = tid >> 1;
    const int akoff = (tid & 1) * 16;
    float amu = 0.f, ars = 0.f;
    if constexpr (AMODE == 1) {
        amu = stats[2 * (bm + arow)];
        ars = stats[2 * (bm + arow) + 1];
    }

    for (int k0 = 0; k0 < K; k0 += 32) {
        if constexpr (AMODE <= 1) {
            const float* Arow = (const float*)Ap + (size_t)(bm + arow) * K + k0 + akoff;
            float vals[16];
            #pragma unroll
            for (int i = 0; i < 4; ++i) {
                const float4 a4 = *reinterpret_cast<const float4*>(Arow + 4 * i);
                vals[4 * i + 0] = a4.x; vals[4 * i + 1] = a4.y;
                vals[4 * i + 2] = a4.z; vals[4 * i + 3] = a4.w;
            }
            if constexpr (AMODE == 1) {
                #pragma unroll
                for (int i = 0; i < 4; ++i) {
                    const float4 g4 = *reinterpret_cast<const float4*>(lng + k0 + akoff + 4 * i);
                    const float4 b4 = *reinterpret_cast<const float4*>(lnb + k0 + akoff + 4 * i);
                    vals[4 * i + 0] = (vals[4 * i + 0] - amu) * ars * g4.x + b4.x;
                    vals[4 * i + 1] = (vals[4 * i + 1] - amu) * ars * g4.y + b4.y;
                    vals[4 * i + 2] = (vals[4 * i + 2] - amu) * ars * g4.z + b4.z;
                    vals[4 * i + 3] = (vals[4 * i + 3] - amu) * ars * g4.w + b4.w;
                }
            }
            #pragma unroll
            for (int i = 0; i < 4; ++i) {
                s16x4 p;
                p[0] = (short)f2bf(vals[4 * i + 0]);
                p[1] = (short)f2bf(vals[4 * i + 1]);
                p[2] = (short)f2bf(vals[4 * i + 2]);
                p[3] = (short)f2bf(vals[4 * i + 3]);
                *reinterpret_cast<s16x4*>(&sA[arow * RS + akoff + 4 * i]) = p;
            }
        } else {
            #pragma unroll
            for (int cc = 0; cc < 2; ++cc) {
                const int c = tid + cc * 256;
                const int row = c >> 2, q = c & 3;
                const u16x8 v = *reinterpret_cast<const u16x8*>(
                    (const unsigned short*)Ap + (size_t)(bm + row) * K + k0 + q * 8);
                *reinterpret_cast<u16x8*>(&sA[row * RS + q * 8]) = v;
            }
        }
        #pragma unroll
        for (int cc = 0; cc < 2; ++cc) {
            const int c = tid + cc * 256;
            const int row = c >> 2, q = c & 3;
            const u16x8 v = *reinterpret_cast<const u16x8*>(
                WT + (size_t)(bn + row) * K + k0 + q * 8);
            *reinterpret_cast<u16x8*>(&sB[row * RS + q * 8]) = v;
        }
        __syncthreads();

        s16x8 af[4], bfr[4];
        #pragma unroll
        for (int i = 0; i < 4; ++i) {
            af[i]  = *reinterpret_cast<const s16x8*>(&sA[(wr * 64 + i * 16 + lr) * RS + kb * 8]);
            bfr[i] = *reinterpret_cast<const s16x8*>(&sB[(wc * 64 + i * 16 + lr) * RS + kb * 8]);
        }
        #pragma unroll
        for (int mt = 0; mt < 4; ++mt)
            #pragma unroll
            for (int nt = 0; nt < 4; ++nt)
                acc[mt][nt] = __builtin_amdgcn_mfma_f32_16x16x32_bf16(
                    af[mt], bfr[nt], acc[mt][nt], 0, 0, 0);
        __syncthreads();
    }

    const int le = lane >> 4;

    if constexpr (MODE == 0 || MODE == 1 || MODE == 4) {
        float bcol[4];
        #pragma unroll
        for (int nt = 0; nt < 4; ++nt)
            bcol[nt] = (MODE == 4) ? 0.f : bias[bn + wc * 64 + nt * 16 + lr];
        #pragma unroll
        for (int mt = 0; mt < 4; ++mt)
            #pragma unroll
            for (int e = 0; e < 4; ++e) {
                const int row = bm + wr * 64 + mt * 16 + le * 4 + e;
                #pragma unroll
                for (int nt = 0; nt < 4; ++nt) {
                    const int col = bn + wc * 64 + nt * 16 + lr;
                    const size_t off = (size_t)row * N + col;
                    float v = acc[mt][nt][e] + bcol[nt];
                    if constexpr (MODE == 0) {
                        v = 0.5f * v * (1.0f + erff(v * 0.70710678118654752f));
                        ((unsigned short*)outp)[off] = f2bf(v);
                    } else {
                        v += res[off];
                        ((float*)outp)[off] = v;
                    }
                }
            }
    } else {  // MODE 2: rope -> (bh,s,d) ; MODE 3: V^T -> (bh,d,s)
        float invfr[4];
        #pragma unroll
        for (int nt = 0; nt < 4; ++nt)
            invfr[nt] = __expf(-ROPE_C_ * (float)((nt * 16 + lr) >> 1));
        #pragma unroll
        for (int mt = 0; mt < 4; ++mt)
            #pragma unroll
            for (int e = 0; e < 4; ++e) {
                const int row  = bm + wr * 64 + mt * 16 + le * 4 + e;
                const int pos  = row & (S_ - 1);
                const int bidx = row >> 11;
                #pragma unroll
                for (int nt = 0; nt < 4; ++nt) {
                    const int col = bn + wc * 64 + nt * 16 + lr;
                    const int hh = col >> 6, d = col & 63;
                    float val = acc[mt][nt][e];
                    if constexpr (MODE == 2) {
                        const float pv = __shfl_xor(val, 1);
                        float sn, cs;
                        sincosf((float)pos * invfr[nt], &sn, &cs);
                        const float outv = ((lr & 1) == 0) ? (val * cs - pv * sn)
                                                           : (pv * sn + val * cs);
                        ((unsigned short*)outp)[(((size_t)bidx * H_ + hh) * S_ + pos) * DH_ + d]
                            = f2bf(outv);
                    } else {
                        ((unsigned short*)outp)[(((size_t)bidx * H_ + hh) * DH_ + d) * S_ + pos]
                            = f2bf(val);
                    }
                }
            }
    }
}

// ---------------------------------------------------------------------------
// MFMA flash attention. Block = 4 waves x 32 queries (QBLK=128), KVBLK=32.
// Q,K bf16 in (bh,s,d); V bf16 TRANSPOSED in (bh,d,s); O bf16 to (b,s,h*64+d).
// Per wave: S^T(32key x 32q) = K*Q^T via 8 mfma; online softmax (state at
// lane&15); P repacked C/D->operand via shfl; O^T(64d x 32q) = V^T*P via
// 8 mfma per tile.  MASKMODE 0: t<=qi ; 1: t<qi or (0,0).
// ---------------------------------------------------------------------------
template<int MASKMODE>
__global__ __launch_bounds__(256)
void flash_mfma(const unsigned short* __restrict__ Qp, const unsigned short* __restrict__ Kp,
                const unsigned short* __restrict__ Vt, unsigned short* __restrict__ O)
{
    __shared__ unsigned short sK[32 * RS];    // [32 keys][64 d] pad RS
    __shared__ unsigned short sV[64 * RS];    // [64 d][32 keys] pad RS
    const int tid  = threadIdx.x;
    const int lane = tid & 63;
    const int w    = tid >> 6;
    const int lr   = lane & 15;
    const int g    = lane >> 4;
    const int qb   = blockIdx.x;
    const int bh   = blockIdx.y;
    const int b    = bh >> 3, h = bh & 7;
    const int q0   = qb * 128 + w * 32;       // wave's first query

    // Q fragments: [qq][dc], 8 bf16 each: Q[q0+qq*16+lr][dc*32 + g*8 + j]
    s16x8 qf[2][2];
    #pragma unroll
    for (int qq = 0; qq < 2; ++qq)
        #pragma unroll
        for (int dc = 0; dc < 2; ++dc)
            qf[qq][dc] = *reinterpret_cast<const s16x8*>(
                Qp + ((size_t)bh * S_ + q0 + qq * 16 + lr) * DH_ + dc * 32 + g * 8);

    f32x4 acc_o[2][4];   // [qq][dt] : O^T[d = dt*16+g*4+e][query = qq*16+lr]
    #pragma unroll
    for (int qq = 0; qq < 2; ++qq)
        #pragma unroll
        for (int dt = 0; dt < 4; ++dt)
            acc_o[qq][dt] = f32x4{0.f, 0.f, 0.f, 0.f};
    float m[2] = {-1e30f, -1e30f}, l[2] = {0.f, 0.f};

    const int ntiles = qb * 4 + 4;
    for (int tile = 0; tile < ntiles; ++tile) {
        const int t0 = tile * 32;
        // stage K: 32 rows x 64 d ; 256 chunks of u16x8
        {
            const int r = tid >> 3, c8 = tid & 7;
            *reinterpret_cast<u16x8*>(&sK[r * RS + c8 * 8]) =
                *reinterpret_cast<const u16x8*>(Kp + ((size_t)bh * S_ + t0 + r) * DH_ + c8 * 8);
            // stage V^T: 64 d-rows x 32 keys
            const int d = tid >> 2, c4 = tid & 3;
            *reinterpret_cast<u16x8*>(&sV[d * RS + c4 * 8]) =
                *reinterpret_cast<const u16x8*>(Vt + ((size_t)bh * DH_ + d) * S_ + t0 + c4 * 8);
        }
        __syncthreads();

        // ---- S^T = K * Q^T ----
        f32x4 accs[2][2];   // [kq][qq]
        #pragma unroll
        for (int kq = 0; kq < 2; ++kq) {
            s16x8 kf0 = *reinterpret_cast<const s16x8*>(&sK[(kq * 16 + lr) * RS + g * 8]);
            s16x8 kf1 = *reinterpret_cast<const s16x8*>(&sK[(kq * 16 + lr) * RS + 32 + g * 8]);
            #pragma unroll
            for (int qq = 0; qq < 2; ++qq) {
                f32x4 a = f32x4{0.f, 0.f, 0.f, 0.f};
                a = __builtin_amdgcn_mfma_f32_16x16x32_bf16(kf0, qf[qq][0], a, 0, 0, 0);
                a = __builtin_amdgcn_mfma_f32_16x16x32_bf16(kf1, qf[qq][1], a, 0, 0, 0);
                accs[kq][qq] = a;
            }
        }

        // ---- online softmax (per query = qq*16+lr) ----
        #pragma unroll
        for (int qq = 0; qq < 2; ++qq) {
            const int qi = q0 + qq * 16 + lr;
            float sc[8];
            #pragma unroll
            for (int kq = 0; kq < 2; ++kq)
                #pragma unroll
                for (int e = 0; e < 4; ++e) {
                    const int t = t0 + kq * 16 + g * 4 + e;
                    bool valid;
                    if (MASKMODE == 0) valid = (t <= qi);
                    else               valid = (t < qi) || (qi == 0 && t == 0);
                    sc[kq * 4 + e] = valid ? accs[kq][qq][e] * SCALE_ : -1e30f;
                }
            float tmax = sc[0];
            #pragma unroll
            for (int i = 1; i < 8; ++i) tmax = fmaxf(tmax, sc[i]);
            tmax = fmaxf(tmax, __shfl_xor(tmax, 16));
            tmax = fmaxf(tmax, __shfl_xor(tmax, 32));
            const float newm = fmaxf(m[qq], tmax);
            unsigned int pk[2][2] = {{0u, 0u}, {0u, 0u}};
            if (newm > -0.9e30f) {
                const float alpha = __expf(m[qq] - newm);
                float psum = 0.f;
                float p[8];
                #pragma unroll
                for (int i = 0; i < 8; ++i) {
                    p[i] = __expf(sc[i] - newm);     // masked: exp(-huge)=0
                    psum += p[i];
                }
                psum += __shfl_xor(psum, 16);
                psum += __shfl_xor(psum, 32);
                l[qq] = l[qq] * alpha + psum;
                m[qq] = newm;
                #pragma unroll
                for (int dt = 0; dt < 4; ++dt) {
                    acc_o[qq][dt][0] *= alpha; acc_o[qq][dt][1] *= alpha;
                    acc_o[qq][dt][2] *= alpha; acc_o[qq][dt][3] *= alpha;
                }
                #pragma unroll
                for (int kq = 0; kq < 2; ++kq)
                    #pragma unroll
                    for (int hh = 0; hh < 2; ++hh)
                        pk[kq][hh] = (unsigned int)f2bf(p[kq * 4 + 2 * hh])
                                   | ((unsigned int)f2bf(p[kq * 4 + 2 * hh + 1]) << 16);
            }
            // ---- repack P: C/D layout -> B-operand layout via shfl ----
            unsigned int af_u[4];
            #pragma unroll
            for (int idx = 0; idx < 4; ++idx) {
                const int sl = lr + 16 * ((2 * g + (idx >> 1)) & 3);
                const unsigned int vA = __shfl(pk[0][idx & 1], sl);
                const unsigned int vB = __shfl(pk[1][idx & 1], sl);
                af_u[idx] = (g >> 1) ? vB : vA;
            }
            const s16x8 pf = __builtin_bit_cast(s16x8, af_u);
            // ---- O^T += V^T * P ----
            #pragma unroll
            for (int dt = 0; dt < 4; ++dt) {
                const s16x8 vf = *reinterpret_cast<const s16x8*>(
                    &sV[(dt * 16 + lr) * RS + g * 8]);
                acc_o[qq][dt] = __builtin_amdgcn_mfma_f32_16x16x32_bf16(
                    vf, pf, acc_o[qq][dt], 0, 0, 0);
            }
        }
        __syncthreads();
    }

    // ---- write O: (b, s, h*64+d) bf16 ----
    #pragma unroll
    for (int qq = 0; qq < 2; ++qq) {
        const float inv = 1.0f / l[qq];
        const int q = q0 + qq * 16 + lr;
        #pragma unroll
        for (int dt = 0; dt < 4; ++dt) {
            u16x4 wv;
            #pragma unroll
            for (int e = 0; e < 4; ++e) wv[e] = f2bf(acc_o[qq][dt][e] * inv);
            *reinterpret_cast<u16x4*>(
                O + ((size_t)b * S_ + q) * DA_ + h * DH_ + dt * 16 + g * 4) = wv;
        }
    }
}

// ---------------------------------------------------------------------------
extern "C" void kernel_launch(void* const* d_in, const int* in_sizes, int n_in,
                              void* d_out, int out_size, void* d_ws, size_t ws_size,
                              hipStream_t stream)
{
    const float* cov_in  = (const float*)d_in[0];
    const float* tgt_in  = (const float*)d_in[1];
    const float* fu_in   = (const float*)d_in[2];
    const float* fc1w    = (const float*)d_in[3];
    const float* fc1b    = (const float*)d_in[4];
    const float* fc2w    = (const float*)d_in[5];
    const float* fc2b    = (const float*)d_in[6];
    const float* icl_wq  = (const float*)d_in[7];
    const float* icl_wk  = (const float*)d_in[8];
    const float* icl_wv  = (const float*)d_in[9];
    const float* icl_wo  = (const float*)d_in[10];
    const float* cov_wq  = (const float*)d_in[11];
    const float* cov_wk  = (const float*)d_in[12];
    const float* cov_wv  = (const float*)d_in[13];
    const float* cov_wo  = (const float*)d_in[14];
    const float* ln_cm_g = (const float*)d_in[15];
    const float* ln_cm_b = (const float*)d_in[16];
    const float* ln_ia_g = (const float*)d_in[17];
    const float* ln_ia_b = (const float*)d_in[18];
    const float* ln_im_g = (const float*)d_in[19];
    const float* ln_im_b = (const float*)d_in[20];

    const size_t NTOK = (size_t)B_ * S_;          // 4096
    float* out_cov = (float*)d_out;
    float* out_tgt = out_cov + NTOK * E_;
    float* out_fu  = out_tgt + NTOK * E_;

    unsigned short* wsb = (unsigned short*)d_ws;
    unsigned short* H16 = wsb;
    unsigned short* P16 = wsb;
    unsigned short* K16 = wsb + 2u * 1024 * 1024;
    unsigned short* V16 = wsb + 4u * 1024 * 1024;   // V^T (bh,d,s)
    unsigned short* O16 = wsb + 6u * 1024 * 1024;
    unsigned short* wT  = wsb + 8u * 1024 * 1024;
    unsigned short* fc1wT   = wT;
    unsigned short* fc2wT   = wT + 2u * 1024 * 1024;
    unsigned short* icl_wqT = wT + 4u * 1024 * 1024;
    unsigned short* icl_wkT = icl_wqT + 512u * 1024;
    unsigned short* icl_wvT = icl_wkT + 512u * 1024;
    unsigned short* icl_woT = icl_wvT + 512u * 1024;
    unsigned short* cov_wqT = icl_woT + 512u * 1024;
    unsigned short* cov_wkT = cov_wqT + 512u * 1024;
    unsigned short* cov_wvT = cov_wkT + 512u * 1024;
    unsigned short* cov_woT = cov_wvT + 512u * 1024;
    float* stM  = (float*)(wsb + 16u * 1024 * 1024);
    float* stIA = stM + 2 * NTOK;

    const int M = (int)NTOK;
    const dim3 blk(256);

    wt_cvt<<<dim3(DMLP_ / 64, E_ / 64), blk, 0, stream>>>(fc1w, fc1wT, E_, DMLP_);
    wt_cvt<<<dim3(E_ / 64, DMLP_ / 64), blk, 0, stream>>>(fc2w, fc2wT, DMLP_, E_);
    wt_cvt<<<dim3(DA_ / 64, E_ / 64), blk, 0, stream>>>(icl_wq, icl_wqT, E_, DA_);
    wt_cvt<<<dim3(DA_ / 64, E_ / 64), blk, 0, stream>>>(icl_wk, icl_wkT, E_, DA_);
    wt_cvt<<<dim3(DA_ / 64, E_ / 64), blk, 0, stream>>>(icl_wv, icl_wvT, E_, DA_);
    wt_cvt<<<dim3(E_ / 64, DA_ / 64), blk, 0, stream>>>(icl_wo, icl_woT, DA_, E_);
    wt_cvt<<<dim3(DA_ / 64, E_ / 64), blk, 0, stream>>>(cov_wq, cov_wqT, E_, DA_);
    wt_cvt<<<dim3(DA_ / 64, E_ / 64), blk, 0, stream>>>(cov_wk, cov_wkT, E_, DA_);
    wt_cvt<<<dim3(DA_ / 64, E_ / 64), blk, 0, stream>>>(cov_wv, cov_wvT, E_, DA_);
    wt_cvt<<<dim3(E_ / 64, DA_ / 64), blk, 0, stream>>>(cov_wo, cov_woT, DA_, E_);

    const dim3 fc1Grid(DMLP_ / 128, M / 128);
    const dim3 fc2Grid(E_ / 128, M / 128);
    const dim3 projGrid(DA_ / 128, M / 128);
    const dim3 oprjGrid(E_ / 128, M / 128);
    const dim3 flashGrid(S_ / 128, B_ * H_);

    // --- cov = covariates + MLP(LN_cm(covariates)) ---
    ln_stats<<<dim3(M), blk, 0, stream>>>(cov_in, stM);
    gemm_mfma<0, 1><<<fc1Grid, blk, 0, stream>>>(cov_in, fc1wT, fc1b, nullptr, H16,
                                                 stM, ln_cm_g, ln_cm_b, M, DMLP_, E_);
    gemm_mfma<1, 2><<<fc2Grid, blk, 0, stream>>>(H16, fc2wT, fc2b, cov_in, out_cov,
                                                 nullptr, nullptr, nullptr, M, E_, DMLP_);

    // --- tgt = targets + MLP(LN_im(functional_update)) ---
    ln_stats<<<dim3(M), blk, 0, stream>>>(fu_in, stM);
    gemm_mfma<0, 1><<<fc1Grid, blk, 0, stream>>>(fu_in, fc1wT, fc1b, nullptr, H16,
                                                 stM, ln_im_g, ln_im_b, M, DMLP_, E_);
    gemm_mfma<1, 2><<<fc2Grid, blk, 0, stream>>>(H16, fc2wT, fc2b, tgt_in, out_tgt,
                                                 nullptr, nullptr, nullptr, M, E_, DMLP_);

    // --- q = LN_ia(cov), applied on the fly ---
    ln_stats<<<dim3(M), blk, 0, stream>>>(out_cov, stIA);

    // --- attn 1 (icl): fu = functional_update + attn(q, q, tgt) ---
    gemm_mfma<2, 1><<<projGrid, blk, 0, stream>>>(out_cov, icl_wqT, nullptr, nullptr, P16,
                                                  stIA, ln_ia_g, ln_ia_b, M, DA_, E_);
    gemm_mfma<2, 1><<<projGrid, blk, 0, stream>>>(out_cov, icl_wkT, nullptr, nullptr, K16,
                                                  stIA, ln_ia_g, ln_ia_b, M, DA_, E_);
    gemm_mfma<3, 0><<<projGrid, blk, 0, stream>>>(out_tgt, icl_wvT, nullptr, nullptr, V16,
                                                  nullptr, nullptr, nullptr, M, DA_, E_);
    flash_mfma<1><<<flashGrid, blk, 0, stream>>>(P16, K16, V16, O16);
    gemm_mfma<4, 2><<<oprjGrid, blk, 0, stream>>>(O16, icl_woT, nullptr, fu_in, out_fu,
                                                  nullptr, nullptr, nullptr, M, E_, DA_);

    // --- attn 2 (cov): cov = cov + attn(q, q, q) ---
    gemm_mfma<2, 1><<<projGrid, blk, 0, stream>>>(out_cov, cov_wqT, nullptr, nullptr, P16,
                                                  stIA, ln_ia_g, ln_ia_b, M, DA_, E_);
    gemm_mfma<2, 1><<<projGrid, blk, 0, stream>>>(out_cov, cov_wkT, nullptr, nullptr, K16,
                                                  stIA, ln_ia_g, ln_ia_b, M, DA_, E_);
    gemm_mfma<3, 1><<<projGrid, blk, 0, stream>>>(out_cov, cov_wvT, nullptr, nullptr, V16,
                                                  stIA, ln_ia_g, ln_ia_b, M, DA_, E_);
    flash_mfma<0><<<flashGrid, blk, 0, stream>>>(P16, K16, V16, O16);
    gemm_mfma<4, 2><<<oprjGrid, blk, 0, stream>>>(O16, cov_woT, nullptr, out_cov, out_cov,
                                                  nullptr, nullptr, nullptr, M, E_, DA_);
}

// Round 6
// 735.596 us; speedup vs baseline: 6.4576x; 1.6492x over previous
//
#include <hip/hip_runtime.h>
#include <math.h>

#define B_ 2
#define S_ 2048
#define E_ 1024
#define H_ 8
#define DH_ 64
#define DA_ 512
#define DMLP_ 2048
#define SCALE_ 0.04419417382415922f   // 1/sqrt(512)
#define LN_EPS_ 1e-5f
#define ROPE_C_ 0.28782313662425575f  // ln(10000)/32

typedef short  s16x8 __attribute__((ext_vector_type(8)));
typedef short  s16x4 __attribute__((ext_vector_type(4)));
typedef unsigned short u16x8 __attribute__((ext_vector_type(8)));
typedef unsigned short u16x4 __attribute__((ext_vector_type(4)));
typedef float  f32x4 __attribute__((ext_vector_type(4)));

static __device__ __forceinline__ float bf2f(unsigned short u) {
    unsigned int x = ((unsigned int)u) << 16;
    return __builtin_bit_cast(float, x);
}
static __device__ __forceinline__ unsigned short f2bf(float f) {
    unsigned int x = __builtin_bit_cast(unsigned int, f);
    x += 0x7fffu + ((x >> 16) & 1u);
    return (unsigned short)(x >> 16);
}

// ---------------------------------------------------------------------------
// Per-row LN stats: stats[2*row]=mean, stats[2*row+1]=rsqrt(var+eps).
// ---------------------------------------------------------------------------
__global__ __launch_bounds__(256)
void ln_stats(const float* __restrict__ x, float* __restrict__ stats)
{
    __shared__ float sm[8];
    const int row = blockIdx.x;
    const int tid = threadIdx.x;
    const float4 v = reinterpret_cast<const float4*>(x + (size_t)row * E_)[tid];
    float s = v.x + v.y + v.z + v.w;
    float q = v.x * v.x + v.y * v.y + v.z * v.z + v.w * v.w;
    #pragma unroll
    for (int o = 32; o > 0; o >>= 1) {
        s += __shfl_down(s, o);
        q += __shfl_down(q, o);
    }
    const int wid = tid >> 6, lane = tid & 63;
    if (lane == 0) { sm[wid] = s; sm[4 + wid] = q; }
    __syncthreads();
    if (tid == 0) {
        const float ts = sm[0] + sm[1] + sm[2] + sm[3];
        const float tq = sm[4] + sm[5] + sm[6] + sm[7];
        const float mu = ts * (1.0f / E_);
        const float var = tq * (1.0f / E_) - mu * mu;
        stats[2 * row]     = mu;
        stats[2 * row + 1] = rsqrtf(var + LN_EPS_);
    }
}

// ---------------------------------------------------------------------------
// Weight transpose + bf16 convert: W [K][N] f32 -> WT [N][K] bf16.
// ---------------------------------------------------------------------------
__global__ __launch_bounds__(256)
void wt_cvt(const float* __restrict__ W, unsigned short* __restrict__ WT, int K, int N)
{
    __shared__ float sm[64][65];
    const int n0 = blockIdx.x * 64;
    const int k0 = blockIdx.y * 64;
    const int t = threadIdx.x;
    const int kr = t >> 2;
    const int nc = (t & 3) * 16;
    #pragma unroll
    for (int i = 0; i < 4; ++i) {
        const float4 v = *reinterpret_cast<const float4*>(W + (size_t)(k0 + kr) * N + n0 + nc + 4 * i);
        sm[kr][nc + 4 * i + 0] = v.x;
        sm[kr][nc + 4 * i + 1] = v.y;
        sm[kr][nc + 4 * i + 2] = v.z;
        sm[kr][nc + 4 * i + 3] = v.w;
    }
    __syncthreads();
    const int nr = t >> 2;
    const int kc = (t & 3) * 16;
    u16x8 a, b;
    #pragma unroll
    for (int i = 0; i < 8; ++i) a[i] = f2bf(sm[kc + i][nr]);
    #pragma unroll
    for (int i = 0; i < 8; ++i) b[i] = f2bf(sm[kc + 8 + i][nr]);
    unsigned short* dst = WT + (size_t)(n0 + nr) * K + k0 + kc;
    *reinterpret_cast<u16x8*>(dst)     = a;
    *reinterpret_cast<u16x8*>(dst + 8) = b;
}

// ---------------------------------------------------------------------------
// bf16 MFMA GEMM, 64x128 tile, BK=32, 256 thr = 4 waves (2x2), wave = 32x64.
// W pre-transposed bf16 WT [N][K].  A: [M][K] f32 (AMODE 0/1) or bf16 (2).
// MODE 0: +bias, gelu, bf16 out          MODE 1: +bias,+res f32 out
// MODE 3: scatter V^T (bh,d,s)           MODE 4: +res f32 out
// MODE 5: fused QKV: per-block segment seg=(bn>>9): 0->Q rope, 1->K rope,
//         2->V^T; dests outp/outk/outv.
// AMODE 0: A f32; 1: A f32+LN; 2: A bf16
// ---------------------------------------------------------------------------
#define RS 40

template<int MODE, int AMODE>
__global__ __launch_bounds__(256)
void gemm_mfma(const void* __restrict__ Ap, const unsigned short* __restrict__ WT,
               const float* __restrict__ bias, const float* res, void* outp,
               void* outk, void* outv,
               const float* __restrict__ stats, const float* __restrict__ lng,
               const float* __restrict__ lnb, int M, int N, int K)
{
    __shared__ unsigned short sA[64 * RS];
    __shared__ unsigned short sB[128 * RS];
    const int tid  = threadIdx.x;
    const int lane = tid & 63;
    const int w    = tid >> 6;
    const int wr   = w >> 1, wc = w & 1;
    const int bm   = blockIdx.y * 64;
    const int bn   = blockIdx.x * 128;
    const int lr   = lane & 15;
    const int kb   = lane >> 4;

    f32x4 acc[2][4];
    #pragma unroll
    for (int i = 0; i < 2; ++i)
        #pragma unroll
        for (int j = 0; j < 4; ++j)
            acc[i][j] = f32x4{0.f, 0.f, 0.f, 0.f};

    const int arow  = tid >> 2;          // 0..63
    const int akoff = (tid & 3) * 8;     // 0,8,16,24
    float amu = 0.f, ars = 0.f;
    if constexpr (AMODE == 1) {
        amu = stats[2 * (bm + arow)];
        ars = stats[2 * (bm + arow) + 1];
    }

    for (int k0 = 0; k0 < K; k0 += 32) {
        // ---- stage A (64 x 32) ----
        if constexpr (AMODE <= 1) {
            const float* Arow = (const float*)Ap + (size_t)(bm + arow) * K + k0 + akoff;
            float vals[8];
            #pragma unroll
            for (int i = 0; i < 2; ++i) {
                const float4 a4 = *reinterpret_cast<const float4*>(Arow + 4 * i);
                vals[4 * i + 0] = a4.x; vals[4 * i + 1] = a4.y;
                vals[4 * i + 2] = a4.z; vals[4 * i + 3] = a4.w;
            }
            if constexpr (AMODE == 1) {
                #pragma unroll
                for (int i = 0; i < 2; ++i) {
                    const float4 g4 = *reinterpret_cast<const float4*>(lng + k0 + akoff + 4 * i);
                    const float4 b4 = *reinterpret_cast<const float4*>(lnb + k0 + akoff + 4 * i);
                    vals[4 * i + 0] = (vals[4 * i + 0] - amu) * ars * g4.x + b4.x;
                    vals[4 * i + 1] = (vals[4 * i + 1] - amu) * ars * g4.y + b4.y;
                    vals[4 * i + 2] = (vals[4 * i + 2] - amu) * ars * g4.z + b4.z;
                    vals[4 * i + 3] = (vals[4 * i + 3] - amu) * ars * g4.w + b4.w;
                }
            }
            u16x8 p;
            #pragma unroll
            for (int i = 0; i < 8; ++i) p[i] = f2bf(vals[i]);
            *reinterpret_cast<u16x8*>(&sA[arow * RS + akoff]) = p;
        } else {
            const u16x8 v = *reinterpret_cast<const u16x8*>(
                (const unsigned short*)Ap + (size_t)(bm + arow) * K + k0 + akoff);
            *reinterpret_cast<u16x8*>(&sA[arow * RS + akoff]) = v;
        }
        // ---- stage B (128 x 32) ----
        #pragma unroll
        for (int cc = 0; cc < 2; ++cc) {
            const int c = tid + cc * 256;
            const int row = c >> 2, q = c & 3;
            const u16x8 v = *reinterpret_cast<const u16x8*>(
                WT + (size_t)(bn + row) * K + k0 + q * 8);
            *reinterpret_cast<u16x8*>(&sB[row * RS + q * 8]) = v;
        }
        __syncthreads();

        s16x8 af[2], bfr[4];
        #pragma unroll
        for (int i = 0; i < 2; ++i)
            af[i]  = *reinterpret_cast<const s16x8*>(&sA[(wr * 32 + i * 16 + lr) * RS + kb * 8]);
        #pragma unroll
        for (int i = 0; i < 4; ++i)
            bfr[i] = *reinterpret_cast<const s16x8*>(&sB[(wc * 64 + i * 16 + lr) * RS + kb * 8]);
        #pragma unroll
        for (int mt = 0; mt < 2; ++mt)
            #pragma unroll
            for (int nt = 0; nt < 4; ++nt)
                acc[mt][nt] = __builtin_amdgcn_mfma_f32_16x16x32_bf16(
                    af[mt], bfr[nt], acc[mt][nt], 0, 0, 0);
        __syncthreads();
    }

    const int le = lane >> 4;   // C/D: col = lane&15, row = le*4 + e

    if constexpr (MODE == 0 || MODE == 1 || MODE == 4) {
        float bcol[4];
        #pragma unroll
        for (int nt = 0; nt < 4; ++nt)
            bcol[nt] = (MODE == 4) ? 0.f : bias[bn + wc * 64 + nt * 16 + lr];
        #pragma unroll
        for (int mt = 0; mt < 2; ++mt)
            #pragma unroll
            for (int e = 0; e < 4; ++e) {
                const int row = bm + wr * 32 + mt * 16 + le * 4 + e;
                #pragma unroll
                for (int nt = 0; nt < 4; ++nt) {
                    const int col = bn + wc * 64 + nt * 16 + lr;
                    const size_t off = (size_t)row * N + col;
                    float v = acc[mt][nt][e] + bcol[nt];
                    if constexpr (MODE == 0) {
                        v = 0.5f * v * (1.0f + erff(v * 0.70710678118654752f));
                        ((unsigned short*)outp)[off] = f2bf(v);
                    } else {
                        v += res[off];
                        ((float*)outp)[off] = v;
                    }
                }
            }
    } else if constexpr (MODE == 3) {   // V^T scatter -> (bh, d, s)
        #pragma unroll
        for (int mt = 0; mt < 2; ++mt)
            #pragma unroll
            for (int e = 0; e < 4; ++e) {
                const int row  = bm + wr * 32 + mt * 16 + le * 4 + e;
                const int pos  = row & (S_ - 1);
                const int bidx = row >> 11;
                #pragma unroll
                for (int nt = 0; nt < 4; ++nt) {
                    const int col = bn + wc * 64 + nt * 16 + lr;
                    const int hh = col >> 6, d = col & 63;
                    ((unsigned short*)outp)[(((size_t)bidx * H_ + hh) * DH_ + d) * S_ + pos]
                        = f2bf(acc[mt][nt][e]);
                }
            }
    } else {  // MODE 5: fused QKV, block-uniform segment
        const int seg = bn >> 9;
        unsigned short* dst = (seg == 0) ? (unsigned short*)outp
                            : (seg == 1) ? (unsigned short*)outk
                                         : (unsigned short*)outv;
        float invfr[4];
        #pragma unroll
        for (int nt = 0; nt < 4; ++nt)
            invfr[nt] = __expf(-ROPE_C_ * (float)((nt * 16 + lr) >> 1));
        #pragma unroll
        for (int mt = 0; mt < 2; ++mt)
            #pragma unroll
            for (int e = 0; e < 4; ++e) {
                const int row  = bm + wr * 32 + mt * 16 + le * 4 + e;
                const int pos  = row & (S_ - 1);
                const int bidx = row >> 11;
                #pragma unroll
                for (int nt = 0; nt < 4; ++nt) {
                    const int col  = bn + wc * 64 + nt * 16 + lr;
                    const int colq = col & 511;
                    const int hh = colq >> 6, d = colq & 63;
                    const float val = acc[mt][nt][e];
                    if (seg < 2) {
                        const float pv = __shfl_xor(val, 1);
                        float sn, cs;
                        sincosf((float)pos * invfr[nt], &sn, &cs);
                        const float outvv = ((lr & 1) == 0) ? (val * cs - pv * sn)
                                                            : (pv * sn + val * cs);
                        dst[(((size_t)bidx * H_ + hh) * S_ + pos) * DH_ + d] = f2bf(outvv);
                    } else {
                        dst[(((size_t)bidx * H_ + hh) * DH_ + d) * S_ + pos] = f2bf(val);
                    }
                }
            }
    }
}

// ---------------------------------------------------------------------------
// MFMA flash attention (unchanged from round 5). Block = 4 waves x 32 q.
// ---------------------------------------------------------------------------
template<int MASKMODE>
__global__ __launch_bounds__(256)
void flash_mfma(const unsigned short* __restrict__ Qp, const unsigned short* __restrict__ Kp,
                const unsigned short* __restrict__ Vt, unsigned short* __restrict__ O)
{
    __shared__ unsigned short sK[32 * RS];
    __shared__ unsigned short sV[64 * RS];
    const int tid  = threadIdx.x;
    const int lane = tid & 63;
    const int w    = tid >> 6;
    const int lr   = lane & 15;
    const int g    = lane >> 4;
    const int qb   = blockIdx.x;
    const int bh   = blockIdx.y;
    const int b    = bh >> 3, h = bh & 7;
    const int q0   = qb * 128 + w * 32;

    s16x8 qf[2][2];
    #pragma unroll
    for (int qq = 0; qq < 2; ++qq)
        #pragma unroll
        for (int dc = 0; dc < 2; ++dc)
            qf[qq][dc] = *reinterpret_cast<const s16x8*>(
                Qp + ((size_t)bh * S_ + q0 + qq * 16 + lr) * DH_ + dc * 32 + g * 8);

    f32x4 acc_o[2][4];
    #pragma unroll
    for (int qq = 0; qq < 2; ++qq)
        #pragma unroll
        for (int dt = 0; dt < 4; ++dt)
            acc_o[qq][dt] = f32x4{0.f, 0.f, 0.f, 0.f};
    float m[2] = {-1e30f, -1e30f}, l[2] = {0.f, 0.f};

    const int ntiles = qb * 4 + 4;
    for (int tile = 0; tile < ntiles; ++tile) {
        const int t0 = tile * 32;
        {
            const int r = tid >> 3, c8 = tid & 7;
            *reinterpret_cast<u16x8*>(&sK[r * RS + c8 * 8]) =
                *reinterpret_cast<const u16x8*>(Kp + ((size_t)bh * S_ + t0 + r) * DH_ + c8 * 8);
            const int d = tid >> 2, c4 = tid & 3;
            *reinterpret_cast<u16x8*>(&sV[d * RS + c4 * 8]) =
                *reinterpret_cast<const u16x8*>(Vt + ((size_t)bh * DH_ + d) * S_ + t0 + c4 * 8);
        }
        __syncthreads();

        f32x4 accs[2][2];
        #pragma unroll
        for (int kq = 0; kq < 2; ++kq) {
            s16x8 kf0 = *reinterpret_cast<const s16x8*>(&sK[(kq * 16 + lr) * RS + g * 8]);
            s16x8 kf1 = *reinterpret_cast<const s16x8*>(&sK[(kq * 16 + lr) * RS + 32 + g * 8]);
            #pragma unroll
            for (int qq = 0; qq < 2; ++qq) {
                f32x4 a = f32x4{0.f, 0.f, 0.f, 0.f};
                a = __builtin_amdgcn_mfma_f32_16x16x32_bf16(kf0, qf[qq][0], a, 0, 0, 0);
                a = __builtin_amdgcn_mfma_f32_16x16x32_bf16(kf1, qf[qq][1], a, 0, 0, 0);
                accs[kq][qq] = a;
            }
        }

        #pragma unroll
        for (int qq = 0; qq < 2; ++qq) {
            const int qi = q0 + qq * 16 + lr;
            float sc[8];
            #pragma unroll
            for (int kq = 0; kq < 2; ++kq)
                #pragma unroll
                for (int e = 0; e < 4; ++e) {
                    const int t = t0 + kq * 16 + g * 4 + e;
                    bool valid;
                    if (MASKMODE == 0) valid = (t <= qi);
                    else               valid = (t < qi) || (qi == 0 && t == 0);
                    sc[kq * 4 + e] = valid ? accs[kq][qq][e] * SCALE_ : -1e30f;
                }
            float tmax = sc[0];
            #pragma unroll
            for (int i = 1; i < 8; ++i) tmax = fmaxf(tmax, sc[i]);
            tmax = fmaxf(tmax, __shfl_xor(tmax, 16));
            tmax = fmaxf(tmax, __shfl_xor(tmax, 32));
            const float newm = fmaxf(m[qq], tmax);
            unsigned int pk[2][2] = {{0u, 0u}, {0u, 0u}};
            if (newm > -0.9e30f) {
                const float alpha = __expf(m[qq] - newm);
                float psum = 0.f;
                float p[8];
                #pragma unroll
                for (int i = 0; i < 8; ++i) {
                    p[i] = __expf(sc[i] - newm);
                    psum += p[i];
                }
                psum += __shfl_xor(psum, 16);
                psum += __shfl_xor(psum, 32);
                l[qq] = l[qq] * alpha + psum;
                m[qq] = newm;
                #pragma unroll
                for (int dt = 0; dt < 4; ++dt) {
                    acc_o[qq][dt][0] *= alpha; acc_o[qq][dt][1] *= alpha;
                    acc_o[qq][dt][2] *= alpha; acc_o[qq][dt][3] *= alpha;
                }
                #pragma unroll
                for (int kq = 0; kq < 2; ++kq)
                    #pragma unroll
                    for (int hh = 0; hh < 2; ++hh)
                        pk[kq][hh] = (unsigned int)f2bf(p[kq * 4 + 2 * hh])
                                   | ((unsigned int)f2bf(p[kq * 4 + 2 * hh + 1]) << 16);
            }
            unsigned int af_u[4];
            #pragma unroll
            for (int idx = 0; idx < 4; ++idx) {
                const int sl = lr + 16 * ((2 * g + (idx >> 1)) & 3);
                const unsigned int vA = __shfl(pk[0][idx & 1], sl);
                const unsigned int vB = __shfl(pk[1][idx & 1], sl);
                af_u[idx] = (g >> 1) ? vB : vA;
            }
            const s16x8 pf = __builtin_bit_cast(s16x8, af_u);
            #pragma unroll
            for (int dt = 0; dt < 4; ++dt) {
                const s16x8 vf = *reinterpret_cast<const s16x8*>(
                    &sV[(dt * 16 + lr) * RS + g * 8]);
                acc_o[qq][dt] = __builtin_amdgcn_mfma_f32_16x16x32_bf16(
                    vf, pf, acc_o[qq][dt], 0, 0, 0);
            }
        }
        __syncthreads();
    }

    #pragma unroll
    for (int qq = 0; qq < 2; ++qq) {
        const float inv = 1.0f / l[qq];
        const int q = q0 + qq * 16 + lr;
        #pragma unroll
        for (int dt = 0; dt < 4; ++dt) {
            u16x4 wv;
            #pragma unroll
            for (int e = 0; e < 4; ++e) wv[e] = f2bf(acc_o[qq][dt][e] * inv);
            *reinterpret_cast<u16x4*>(
                O + ((size_t)b * S_ + q) * DA_ + h * DH_ + dt * 16 + g * 4) = wv;
        }
    }
}

// ---------------------------------------------------------------------------
extern "C" void kernel_launch(void* const* d_in, const int* in_sizes, int n_in,
                              void* d_out, int out_size, void* d_ws, size_t ws_size,
                              hipStream_t stream)
{
    const float* cov_in  = (const float*)d_in[0];
    const float* tgt_in  = (const float*)d_in[1];
    const float* fu_in   = (const float*)d_in[2];
    const float* fc1w    = (const float*)d_in[3];
    const float* fc1b    = (const float*)d_in[4];
    const float* fc2w    = (const float*)d_in[5];
    const float* fc2b    = (const float*)d_in[6];
    const float* icl_wq  = (const float*)d_in[7];
    const float* icl_wk  = (const float*)d_in[8];
    const float* icl_wv  = (const float*)d_in[9];
    const float* icl_wo  = (const float*)d_in[10];
    const float* cov_wq  = (const float*)d_in[11];
    const float* cov_wk  = (const float*)d_in[12];
    const float* cov_wv  = (const float*)d_in[13];
    const float* cov_wo  = (const float*)d_in[14];
    const float* ln_cm_g = (const float*)d_in[15];
    const float* ln_cm_b = (const float*)d_in[16];
    const float* ln_ia_g = (const float*)d_in[17];
    const float* ln_ia_b = (const float*)d_in[18];
    const float* ln_im_g = (const float*)d_in[19];
    const float* ln_im_b = (const float*)d_in[20];

    const size_t NTOK = (size_t)B_ * S_;          // 4096
    float* out_cov = (float*)d_out;
    float* out_tgt = out_cov + NTOK * E_;
    float* out_fu  = out_tgt + NTOK * E_;

    unsigned short* wsb = (unsigned short*)d_ws;
    unsigned short* H16 = wsb;
    unsigned short* P16 = wsb;
    unsigned short* K16 = wsb + 2u * 1024 * 1024;
    unsigned short* V16 = wsb + 4u * 1024 * 1024;   // V^T (bh,d,s)
    unsigned short* O16 = wsb + 6u * 1024 * 1024;
    unsigned short* wT  = wsb + 8u * 1024 * 1024;
    unsigned short* fc1wT   = wT;
    unsigned short* fc2wT   = wT + 2u * 1024 * 1024;
    unsigned short* icl_wqT = wT + 4u * 1024 * 1024;    // qk fused: [1024][1024]
    unsigned short* icl_wkT = icl_wqT + 512u * 1024;
    unsigned short* icl_wvT = icl_wkT + 512u * 1024;
    unsigned short* icl_woT = icl_wvT + 512u * 1024;
    unsigned short* cov_wqT = icl_woT + 512u * 1024;    // qkv fused: [1536][1024]
    unsigned short* cov_wkT = cov_wqT + 512u * 1024;
    unsigned short* cov_wvT = cov_wkT + 512u * 1024;
    unsigned short* cov_woT = cov_wvT + 512u * 1024;
    float* stM  = (float*)(wsb + 16u * 1024 * 1024);
    float* stIA = stM + 2 * NTOK;

    const int M = (int)NTOK;
    const dim3 blk(256);

    wt_cvt<<<dim3(DMLP_ / 64, E_ / 64), blk, 0, stream>>>(fc1w, fc1wT, E_, DMLP_);
    wt_cvt<<<dim3(E_ / 64, DMLP_ / 64), blk, 0, stream>>>(fc2w, fc2wT, DMLP_, E_);
    wt_cvt<<<dim3(DA_ / 64, E_ / 64), blk, 0, stream>>>(icl_wq, icl_wqT, E_, DA_);
    wt_cvt<<<dim3(DA_ / 64, E_ / 64), blk, 0, stream>>>(icl_wk, icl_wkT, E_, DA_);
    wt_cvt<<<dim3(DA_ / 64, E_ / 64), blk, 0, stream>>>(icl_wv, icl_wvT, E_, DA_);
    wt_cvt<<<dim3(E_ / 64, DA_ / 64), blk, 0, stream>>>(icl_wo, icl_woT, DA_, E_);
    wt_cvt<<<dim3(DA_ / 64, E_ / 64), blk, 0, stream>>>(cov_wq, cov_wqT, E_, DA_);
    wt_cvt<<<dim3(DA_ / 64, E_ / 64), blk, 0, stream>>>(cov_wk, cov_wkT, E_, DA_);
    wt_cvt<<<dim3(DA_ / 64, E_ / 64), blk, 0, stream>>>(cov_wv, cov_wvT, E_, DA_);
    wt_cvt<<<dim3(E_ / 64, DA_ / 64), blk, 0, stream>>>(cov_wo, cov_woT, DA_, E_);

    const dim3 fc1Grid(DMLP_ / 128, M / 64);
    const dim3 fc2Grid(E_ / 128, M / 64);
    const dim3 qk1Grid(1024 / 128, M / 64);
    const dim3 v1Grid(DA_ / 128, M / 64);
    const dim3 qkv2Grid(1536 / 128, M / 64);
    const dim3 oprjGrid(E_ / 128, M / 64);
    const dim3 flashGrid(S_ / 128, B_ * H_);

    // --- cov = covariates + MLP(LN_cm(covariates)) ---
    ln_stats<<<dim3(M), blk, 0, stream>>>(cov_in, stM);
    gemm_mfma<0, 1><<<fc1Grid, blk, 0, stream>>>(cov_in, fc1wT, fc1b, nullptr, H16,
        nullptr, nullptr, stM, ln_cm_g, ln_cm_b, M, DMLP_, E_);
    gemm_mfma<1, 2><<<fc2Grid, blk, 0, stream>>>(H16, fc2wT, fc2b, cov_in, out_cov,
        nullptr, nullptr, nullptr, nullptr, nullptr, M, E_, DMLP_);

    // --- tgt = targets + MLP(LN_im(functional_update)) ---
    ln_stats<<<dim3(M), blk, 0, stream>>>(fu_in, stM);
    gemm_mfma<0, 1><<<fc1Grid, blk, 0, stream>>>(fu_in, fc1wT, fc1b, nullptr, H16,
        nullptr, nullptr, stM, ln_im_g, ln_im_b, M, DMLP_, E_);
    gemm_mfma<1, 2><<<fc2Grid, blk, 0, stream>>>(H16, fc2wT, fc2b, tgt_in, out_tgt,
        nullptr, nullptr, nullptr, nullptr, nullptr, M, E_, DMLP_);

    // --- q = LN_ia(cov), applied on the fly ---
    ln_stats<<<dim3(M), blk, 0, stream>>>(out_cov, stIA);

    // --- attn 1 (icl): fu = functional_update + attn(q, q, tgt) ---
    gemm_mfma<5, 1><<<qk1Grid, blk, 0, stream>>>(out_cov, icl_wqT, nullptr, nullptr, P16,
        K16, nullptr, stIA, ln_ia_g, ln_ia_b, M, 1024, E_);
    gemm_mfma<3, 0><<<v1Grid, blk, 0, stream>>>(out_tgt, icl_wvT, nullptr, nullptr, V16,
        nullptr, nullptr, nullptr, nullptr, nullptr, M, DA_, E_);
    flash_mfma<1><<<flashGrid, blk, 0, stream>>>(P16, K16, V16, O16);
    gemm_mfma<4, 2><<<oprjGrid, blk, 0, stream>>>(O16, icl_woT, nullptr, fu_in, out_fu,
        nullptr, nullptr, nullptr, nullptr, nullptr, M, E_, DA_);

    // --- attn 2 (cov): cov = cov + attn(q, q, q) ---
    gemm_mfma<5, 1><<<qkv2Grid, blk, 0, stream>>>(out_cov, cov_wqT, nullptr, nullptr, P16,
        K16, V16, stIA, ln_ia_g, ln_ia_b, M, 1536, E_);
    flash_mfma<0><<<flashGrid, blk, 0, stream>>>(P16, K16, V16, O16);
    gemm_mfma<4, 2><<<oprjGrid, blk, 0, stream>>>(O16, cov_woT, nullptr, out_cov, out_cov,
        nullptr, nullptr, nullptr, nullptr, nullptr, M, E_, DA_);
}